// Round 2
// baseline (1466.190 us; speedup 1.0000x reference)
//
#include <hip/hip_runtime.h>
#include <math.h>

// ---- fixed problem dims ----
constexpr int Bb  = 16;
constexpr int Tt  = 16;
constexpr int Nn  = 196;   // patches (14x14)
constexpr int Cc  = 768;
constexpr int Aa  = 192;
constexpr int KK  = 8;     // TOPK
constexpr int NCAND = 16;  // fp32 candidates refined in f64
constexpr int BT  = Bb * Tt;            // 256
constexpr int BTN = BT * Nn;            // 50176
constexpr size_t SZ = (size_t)BTN * Aa; // 9,633,792 floats

static __device__ __forceinline__ float gelu_f(float x) {
  return 0.5f * x * (1.0f + erff(x * 0.7071067811865476f));
}

// ============================================================
// Generic fp32 GEMM: C[m,n] = sum_k A[m,k] * W[n,k] (+bias) (+epilogue)
// ============================================================
template <int ROWMAP, int BIAS, int EPI>
__global__ __launch_bounds__(256) void gemm_nt(
    const float* __restrict__ Ain, const float* __restrict__ W,
    const float* __restrict__ bias, float* __restrict__ Cout,
    const float* __restrict__ resid, int M, int Nc, int K) {
  __shared__ float As[16][68];
  __shared__ float Ws[16][68];
  const int tid = threadIdx.x;
  const int tx = tid & 15, ty = tid >> 4;
  const int row0 = blockIdx.x * 64;
  const int col0 = blockIdx.y * 64;
  const int lm = tid >> 2;         // 0..63
  const int lk = (tid & 3) << 2;   // 0,4,8,12

  const float* Arow;
  {
    int r = row0 + lm;
    if (ROWMAP) {
      int bt = r / Nn;
      int n = r - bt * Nn;
      Arow = Ain + (size_t)(bt * (Nn + 1) + 1 + n) * K;
    } else {
      Arow = Ain + (size_t)r * K;
    }
  }
  const float* Wrow = W + (size_t)(col0 + lm) * K;

  float acc[4][4] = {};
  for (int k0 = 0; k0 < K; k0 += 16) {
    float4 av = *(const float4*)(Arow + k0 + lk);
    float4 wv = *(const float4*)(Wrow + k0 + lk);
    As[lk + 0][lm] = av.x; As[lk + 1][lm] = av.y;
    As[lk + 2][lm] = av.z; As[lk + 3][lm] = av.w;
    Ws[lk + 0][lm] = wv.x; Ws[lk + 1][lm] = wv.y;
    Ws[lk + 2][lm] = wv.z; Ws[lk + 3][lm] = wv.w;
    __syncthreads();
#pragma unroll
    for (int kk = 0; kk < 16; ++kk) {
      float4 af = *(const float4*)&As[kk][ty * 4];
      float4 wf = *(const float4*)&Ws[kk][tx * 4];
      acc[0][0] = fmaf(af.x, wf.x, acc[0][0]);
      acc[0][1] = fmaf(af.x, wf.y, acc[0][1]);
      acc[0][2] = fmaf(af.x, wf.z, acc[0][2]);
      acc[0][3] = fmaf(af.x, wf.w, acc[0][3]);
      acc[1][0] = fmaf(af.y, wf.x, acc[1][0]);
      acc[1][1] = fmaf(af.y, wf.y, acc[1][1]);
      acc[1][2] = fmaf(af.y, wf.z, acc[1][2]);
      acc[1][3] = fmaf(af.y, wf.w, acc[1][3]);
      acc[2][0] = fmaf(af.z, wf.x, acc[2][0]);
      acc[2][1] = fmaf(af.z, wf.y, acc[2][1]);
      acc[2][2] = fmaf(af.z, wf.z, acc[2][2]);
      acc[2][3] = fmaf(af.z, wf.w, acc[2][3]);
      acc[3][0] = fmaf(af.w, wf.x, acc[3][0]);
      acc[3][1] = fmaf(af.w, wf.y, acc[3][1]);
      acc[3][2] = fmaf(af.w, wf.z, acc[3][2]);
      acc[3][3] = fmaf(af.w, wf.w, acc[3][3]);
    }
    __syncthreads();
  }
#pragma unroll
  for (int i = 0; i < 4; ++i) {
    int r = row0 + ty * 4 + i;
#pragma unroll
    for (int j = 0; j < 4; ++j) {
      int c = col0 + tx * 4 + j;
      float v = acc[i][j];
      if (BIAS) v += bias[c];
      if (EPI == 1) v = gelu_f(v);
      if (EPI == 2) {
        int bt = r / Nn;
        int n = r - bt * Nn;
        size_t off = (size_t)(bt * (Nn + 1) + 1 + n) * Nc + c;
        Cout[off] = resid[off] + v;
      } else {
        Cout[(size_t)r * Nc + c] = v;
      }
    }
  }
}

// ============================================================
// delta + per-(b,t) |delta| partials
// ============================================================
__global__ void delta_kernel(const float* __restrict__ ph,
                             float* __restrict__ delta,
                             float* __restrict__ dppart) {
  int bt = blockIdx.x;
  int t = bt & 15;
  int a = threadIdx.x;
  const float* cur = ph + (size_t)bt * Nn * Aa + a;
  float* dl = delta + (size_t)bt * Nn * Aa + a;
  float acc = 0.f;
  if (t == 0) {
    for (int n = 0; n < Nn; ++n) dl[(size_t)n * Aa] = 0.f;
  } else {
    const float* prev = cur - (size_t)Nn * Aa;
    for (int n = 0; n < Nn; ++n) {
      float d = cur[(size_t)n * Aa] - prev[(size_t)n * Aa];
      dl[(size_t)n * Aa] = d;
      acc += fabsf(d);
    }
  }
  dppart[bt * Aa + a] = acc;
}

// sal[row] = mean_a |delta[row,a]| (fp32, candidate stage only)
__global__ void sal_kernel(const float* __restrict__ delta,
                           float* __restrict__ sal) {
  int row = blockIdx.x * 4 + (threadIdx.x >> 6);
  int lane = threadIdx.x & 63;
  const float* d = delta + (size_t)row * Aa;
  float s = fabsf(d[lane]) + fabsf(d[lane + 64]) + fabsf(d[lane + 128]);
#pragma unroll
  for (int off = 32; off > 0; off >>= 1) s += __shfl_xor(s, off, 64);
  if (lane == 0) sal[row] = s * (1.0f / 192.0f);
}

// ============================================================
// top-16 fp32 candidates per (b,t); descending val, ties -> smaller n
// ============================================================
__global__ void topcand_kernel(const float* __restrict__ sal,
                               int* __restrict__ cand) {
  int bt = blockIdx.x;
  int lane = threadIdx.x;
  unsigned long long key[4];
#pragma unroll
  for (int j = 0; j < 4; ++j) {
    int n = lane + 64 * j;
    if (n < Nn) {
      unsigned fb = __float_as_uint(sal[(size_t)bt * Nn + n]);
      key[j] = ((unsigned long long)fb << 32) |
               (unsigned long long)(0xFFFFFFFFu - (unsigned)n);
    } else {
      key[j] = 0ULL;
    }
  }
  for (int r = 0; r < NCAND; ++r) {
    unsigned long long m = key[0];
    if (key[1] > m) m = key[1];
    if (key[2] > m) m = key[2];
    if (key[3] > m) m = key[3];
#pragma unroll
    for (int off = 32; off > 0; off >>= 1) {
      unsigned long long o = __shfl_xor(m, off, 64);
      if (o > m) m = o;
    }
    if (lane == 0)
      cand[bt * NCAND + r] = (int)(0xFFFFFFFFu - (unsigned)(m & 0xFFFFFFFFull));
#pragma unroll
    for (int j = 0; j < 4; ++j)
      if (key[j] == m) key[j] = 0ULL;
  }
}

// ============================================================
// f64 refine: sal64 = mean_a |sum_c (x_t - x_{t-1})[n,c] * down_w[a,c]|
// grid (BT, 2): 8 candidates per block; block = 192 threads (a)
// ============================================================
__global__ __launch_bounds__(192) void refine_kernel(
    const float* __restrict__ x, const float* __restrict__ down_w,
    const int* __restrict__ cand, double* __restrict__ sal64) {
  int bt = blockIdx.x;
  int grp = blockIdx.y;
  int t = bt & 15;
  int a = threadIdx.x;
  if (t == 0) {
    if (a < 8) sal64[bt * NCAND + grp * 8 + a] = 0.0;
    return;
  }
  __shared__ double sdiff[8][Cc];
  __shared__ double sabs[8][Aa];
  const float* xt = x + (size_t)bt * (Nn + 1) * Cc;
  const float* xp = xt - (size_t)(Nn + 1) * Cc;
  for (int g = 0; g < 8; ++g) {
    int n = cand[bt * NCAND + grp * 8 + g];
    const float* rt = xt + (size_t)(1 + n) * Cc;
    const float* rp = xp + (size_t)(1 + n) * Cc;
    for (int c = a; c < Cc; c += 192)
      sdiff[g][c] = (double)rt[c] - (double)rp[c];
  }
  __syncthreads();
  double acc[8] = {};
  const float* wrow = down_w + (size_t)a * Cc;
  for (int c0 = 0; c0 < Cc; c0 += 4) {
    float4 w4 = *(const float4*)(wrow + c0);
#pragma unroll
    for (int g = 0; g < 8; ++g) {
      acc[g] += (double)w4.x * sdiff[g][c0] + (double)w4.y * sdiff[g][c0 + 1] +
                (double)w4.z * sdiff[g][c0 + 2] +
                (double)w4.w * sdiff[g][c0 + 3];
    }
  }
#pragma unroll
  for (int g = 0; g < 8; ++g) sabs[g][a] = fabs(acc[g]);
  __syncthreads();
  if (a < 8) {
    double s = 0.0;
    for (int i = 0; i < Aa; ++i) s += sabs[a][i];
    sal64[bt * NCAND + grp * 8 + a] = s * (1.0 / 192.0);
  }
}

// final top-8 by (sal64 desc, n asc)
__global__ void select_kernel(const double* __restrict__ sal64,
                              const int* __restrict__ cand,
                              int* __restrict__ idx) {
  int bt = blockIdx.x;
  int t = bt & 15;
  if (threadIdx.x != 0) return;
  if (t == 0) {
    for (int r = 0; r < KK; ++r) idx[bt * KK + r] = r;
    return;
  }
  double v[NCAND];
  int nn[NCAND];
  bool used[NCAND];
  for (int i = 0; i < NCAND; ++i) {
    v[i] = sal64[bt * NCAND + i];
    nn[i] = cand[bt * NCAND + i];
    used[i] = false;
  }
  for (int r = 0; r < KK; ++r) {
    int best = -1;
    for (int i = 0; i < NCAND; ++i) {
      if (used[i]) continue;
      if (best < 0 || v[i] > v[best] ||
          (v[i] == v[best] && nn[i] < nn[best]))
        best = i;
    }
    used[best] = true;
    idx[bt * KK + r] = nn[best];
  }
}

// ============================================================
// fused anchor attention: one block per (b,k)
// ============================================================
__global__ __launch_bounds__(256) void attn_kernel(
    const float* __restrict__ ph, const float* __restrict__ delta,
    const int* __restrict__ idx, const float* __restrict__ win,
    const float* __restrict__ bin, const float* __restrict__ wout,
    const float* __restrict__ bout, const float* __restrict__ wproj,
    const float* __restrict__ bproj, float* __restrict__ attout,
    float* __restrict__ appart) {
  int bk = blockIdx.x;
  int b = bk >> 3, k = bk & 7;
  __shared__ float stok[16 * 192];
  __shared__ float sqkv[16 * 576];
  __shared__ float ssc[4][16][16];
  __shared__ float so[16 * 192];
  int tid = threadIdx.x;

  for (int e = tid; e < 16 * 192; e += 256) {
    int tt = e / 192, a = e % 192;
    int n = idx[(b * 16 + tt) * KK + k];
    size_t off = ((size_t)(b * 16 + tt) * Nn + n) * Aa + a;
    stok[e] = ph[off] + delta[off];
  }
  __syncthreads();

  for (int e = tid; e < 16 * 576; e += 256) {
    int tt = e / 576, j = e % 576;
    const float* w = win + (size_t)j * 192;
    const float* tk = stok + tt * 192;
    float s = bin[j];
#pragma unroll 8
    for (int a2 = 0; a2 < 192; ++a2) s = fmaf(tk[a2], w[a2], s);
    sqkv[e] = s;
  }
  __syncthreads();

  int h = tid >> 6, lane = tid & 63;
#pragma unroll
  for (int s4 = 0; s4 < 4; ++s4) {
    int e = lane + 64 * s4;
    int i = e >> 4, j = e & 15;
    const float* q = sqkv + i * 576 + h * 48;
    const float* kk2 = sqkv + j * 576 + 192 + h * 48;
    float s = 0.f;
#pragma unroll 8
    for (int d = 0; d < 48; ++d) s = fmaf(q[d], kk2[d], s);
    ssc[h][i][j] = s * 0.14433756729740643f;  // 1/sqrt(48)
  }
  __syncthreads();
  if (lane < 16) {
    float* r = ssc[h][lane];
    float mx = r[0];
    for (int j = 1; j < 16; ++j) mx = fmaxf(mx, r[j]);
    float sum = 0.f;
    for (int j = 0; j < 16; ++j) {
      float ev = expf(r[j] - mx);
      r[j] = ev;
      sum += ev;
    }
    float inv = 1.0f / sum;
    for (int j = 0; j < 16; ++j) r[j] *= inv;
  }
  __syncthreads();
#pragma unroll
  for (int s4 = 0; s4 < 12; ++s4) {
    int e = lane + 64 * s4;
    int i = e / 48, d = e % 48;
    float s = 0.f;
#pragma unroll
    for (int j = 0; j < 16; ++j)
      s = fmaf(ssc[h][i][j], sqkv[j * 576 + 384 + h * 48 + d], s);
    so[i * 192 + h * 48 + d] = s;
  }
  __syncthreads();
  for (int e = tid; e < 16 * 192; e += 256) {
    int tt = e / 192, a = e % 192;
    const float* w = wout + (size_t)a * 192;
    const float* o = so + tt * 192;
    float s = bout[a];
#pragma unroll 8
    for (int c2 = 0; c2 < 192; ++c2) s = fmaf(o[c2], w[c2], s);
    stok[e] = s;
  }
  __syncthreads();
  for (int e = tid; e < 16 * 192; e += 256) {
    int tt = e / 192, a = e % 192;
    const float* w = wproj + (size_t)a * 192;
    const float* o = stok + tt * 192;
    float s = bproj[a];
#pragma unroll 8
    for (int c2 = 0; c2 < 192; ++c2) s = fmaf(o[c2], w[c2], s);
    attout[(size_t)bk * (16 * 192) + e] = s;
    so[e] = s;
  }
  __syncthreads();
  if (tid < 192) {
    float s = 0.f;
    for (int tt = 0; tt < 16; ++tt) s += so[tt * 192 + tid];
    appart[bk * Aa + tid] = s;
  }
}

// depthwise 3x3 SAME conv over 14x14 + gelu
__global__ void conv2d_kernel(const float* __restrict__ ph,
                              const float* __restrict__ ldw,
                              float* __restrict__ og) {
  size_t e = (size_t)blockIdx.x * 256 + threadIdx.x;
  int a = (int)(e % Aa);
  size_t r = e / Aa;
  int n = (int)(r % Nn);
  int bt = (int)(r / Nn);
  int y = n / 14, x = n % 14;
  const float* base = ph + (size_t)bt * Nn * Aa + a;
  const float* w = ldw + a * 9;
  float s = 0.f;
#pragma unroll
  for (int dy = -1; dy <= 1; ++dy) {
    int yy = y + dy;
    if (yy < 0 || yy >= 14) continue;
#pragma unroll
    for (int dx = -1; dx <= 1; ++dx) {
      int xc = x + dx;
      if (xc < 0 || xc >= 14) continue;
      s = fmaf(base[(size_t)(yy * 14 + xc) * Aa], w[(dy + 1) * 3 + (dx + 1)], s);
    }
  }
  og[e] = gelu_f(s);
}

// depthwise k=3 SAME conv over t + gelu
__global__ void conv1d_kernel(const float* __restrict__ delta,
                              const float* __restrict__ tdw,
                              float* __restrict__ og) {
  size_t e = (size_t)blockIdx.x * 256 + threadIdx.x;
  int a = (int)(e % Aa);
  size_t r = e / Aa;
  int n = (int)(r % Nn);
  int bt = (int)(r / Nn);
  int t = bt & 15, b = bt >> 4;
  const float* w = tdw + a * 3;
  float s = 0.f;
#pragma unroll
  for (int j = 0; j < 3; ++j) {
    int tt = t + j - 1;
    if (tt >= 0 && tt < Tt)
      s = fmaf(delta[((size_t)(b * Tt + tt) * Nn + n) * Aa + a], w[j], s);
  }
  og[e] = gelu_f(s);
}

// in-place LayerNorm over last dim (192); one wave per row
__global__ void ln_kernel(float* __restrict__ buf, const float* __restrict__ g,
                          const float* __restrict__ bb) {
  size_t row = (size_t)blockIdx.x * 4 + (threadIdx.x >> 6);
  int lane = threadIdx.x & 63;
  float* p = buf + row * Aa;
  float v0 = p[lane], v1 = p[lane + 64], v2 = p[lane + 128];
  float s = v0 + v1 + v2;
#pragma unroll
  for (int off = 32; off > 0; off >>= 1) s += __shfl_xor(s, off, 64);
  float m = s * (1.0f / 192.0f);
  float d0 = v0 - m, d1 = v1 - m, d2 = v2 - m;
  float ss = d0 * d0 + d1 * d1 + d2 * d2;
#pragma unroll
  for (int off = 32; off > 0; off >>= 1) ss += __shfl_xor(ss, off, 64);
  float inv = rsqrtf(ss * (1.0f / 192.0f) + 1e-5f);
  p[lane] = d0 * inv * g[lane] + bb[lane];
  p[lane + 64] = d1 * inv * g[lane + 64] + bb[lane + 64];
  p[lane + 128] = d2 * inv * g[lane + 128] + bb[lane + 128];
}

// scatter anchor_tok into zeroed anchor_map
__global__ void scatter_kernel(const float* __restrict__ attout,
                               const int* __restrict__ idx,
                               float* __restrict__ amap) {
  int bt = blockIdx.x;
  int b = bt >> 4, t = bt & 15;
  for (int e = threadIdx.x; e < KK * Aa; e += 256) {
    int k = e / Aa, a = e % Aa;
    int n = idx[bt * KK + k];
    amap[((size_t)bt * Nn + n) * Aa + a] =
        attout[((size_t)(b * KK + k) * Tt + t) * Aa + a];
  }
}

// gate MLP + 3-way softmax; one block per b, 192 threads
__global__ void gate_kernel(const float* __restrict__ dppart,
                            const float* __restrict__ appart,
                            const float* __restrict__ w1,
                            const float* __restrict__ b1,
                            const float* __restrict__ w2,
                            const float* __restrict__ b2,
                            float* __restrict__ gw) {
  int b = blockIdx.x;
  __shared__ float sg[2 * Aa];
  __shared__ float sh[Aa];
  int tid = threadIdx.x;
  {
    float d = 0.f;
    for (int t2 = 0; t2 < Tt; ++t2) d += dppart[(b * Tt + t2) * Aa + tid];
    sg[tid] = d * (1.0f / 3136.0f);
    float a = 0.f;
    for (int k2 = 0; k2 < KK; ++k2) a += appart[(b * KK + k2) * Aa + tid];
    sg[Aa + tid] = a * (1.0f / 128.0f);
  }
  __syncthreads();
  {
    const float* w = w1 + (size_t)tid * 2 * Aa;
    float s = b1[tid];
#pragma unroll 8
    for (int j = 0; j < 2 * Aa; ++j) s = fmaf(sg[j], w[j], s);
    sh[tid] = gelu_f(s);
  }
  __syncthreads();
  float v[3];
#pragma unroll
  for (int i = 0; i < 3; ++i) {
    const float* w = w2 + (size_t)(i * Aa + tid) * Aa;
    float s = b2[i * Aa + tid];
#pragma unroll 8
    for (int j = 0; j < Aa; ++j) s = fmaf(sh[j], w[j], s);
    v[i] = s;
  }
  float mx = fmaxf(v[0], fmaxf(v[1], v[2]));
  float e0 = expf(v[0] - mx), e1 = expf(v[1] - mx), e2 = expf(v[2] - mx);
  float inv = 1.0f / (e0 + e1 + e2);
  gw[(b * 3 + 0) * Aa + tid] = e0 * inv;
  gw[(b * 3 + 1) * Aa + tid] = e1 * inv;
  gw[(b * 3 + 2) * Aa + tid] = e2 * inv;
}

// fused = gw0*local + gw1*trans + gw2*amap; fmean[bt,a] = sum_n fused
__global__ void fused_kernel(const float* __restrict__ local,
                             const float* __restrict__ trans,
                             const float* __restrict__ amap,
                             const float* __restrict__ gw,
                             float* __restrict__ fused,
                             float* __restrict__ fmean) {
  int bt = blockIdx.x;
  int b = bt >> 4;
  int a = threadIdx.x;
  float g0 = gw[(b * 3 + 0) * Aa + a];
  float g1 = gw[(b * 3 + 1) * Aa + a];
  float g2 = gw[(b * 3 + 2) * Aa + a];
  size_t base = (size_t)bt * Nn * Aa + a;
  float acc = 0.f;
  for (int n = 0; n < Nn; ++n) {
    size_t o = base + (size_t)n * Aa;
    float f = g0 * local[o] + g1 * trans[o] + g2 * amap[o];
    fused[o] = f;
    acc += f;
  }
  fmean[bt * Aa + a] = acc;
}

// cls_out = cls_tok + (mean_n fused) @ cls_w.T + cls_b
__global__ void cls_kernel(const float* __restrict__ fmean,
                           const float* __restrict__ cw,
                           const float* __restrict__ cb,
                           const float* __restrict__ x,
                           float* __restrict__ out) {
  int bt = blockIdx.x;
  __shared__ float fm[Aa];
  int tid = threadIdx.x;
  if (tid < Aa) fm[tid] = fmean[bt * Aa + tid] * (1.0f / 196.0f);
  __syncthreads();
  for (int c = tid; c < Cc; c += 256) {
    const float* w = cw + (size_t)c * Aa;
    float s = cb[c];
#pragma unroll 8
    for (int a = 0; a < Aa; ++a) s = fmaf(fm[a], w[a], s);
    size_t off = (size_t)bt * (Nn + 1) * Cc + c;
    out[off] = x[off] + s;
  }
}

// ============================================================
extern "C" void kernel_launch(void* const* d_in, const int* in_sizes, int n_in,
                              void* d_out, int out_size, void* d_ws,
                              size_t ws_size, hipStream_t stream) {
  const float* x = (const float*)d_in[0];
  const float* down_w = (const float*)d_in[1];
  const float* down_b = (const float*)d_in[2];
  const float* ldw_w = (const float*)d_in[3];
  const float* lpw_w = (const float*)d_in[4];
  const float* lnorm_g = (const float*)d_in[5];
  const float* lnorm_b = (const float*)d_in[6];
  const float* tdw_w = (const float*)d_in[7];
  const float* tpw_w = (const float*)d_in[8];
  const float* tmlp_w1 = (const float*)d_in[9];
  const float* tmlp_b1 = (const float*)d_in[10];
  const float* tmlp_w2 = (const float*)d_in[11];
  const float* tmlp_b2 = (const float*)d_in[12];
  const float* tnorm_g = (const float*)d_in[13];
  const float* tnorm_b = (const float*)d_in[14];
  const float* attn_in_w = (const float*)d_in[15];
  const float* attn_in_b = (const float*)d_in[16];
  const float* attn_out_w = (const float*)d_in[17];
  const float* attn_out_b = (const float*)d_in[18];
  const float* aproj_w = (const float*)d_in[19];
  const float* aproj_b = (const float*)d_in[20];
  const float* anorm_g = (const float*)d_in[21];
  const float* anorm_b = (const float*)d_in[22];
  const float* gate_w1 = (const float*)d_in[23];
  const float* gate_b1 = (const float*)d_in[24];
  const float* gate_w2 = (const float*)d_in[25];
  const float* gate_b2 = (const float*)d_in[26];
  const float* up_w = (const float*)d_in[27];
  const float* up_b = (const float*)d_in[28];
  const float* cls_w = (const float*)d_in[29];
  const float* cls_b = (const float*)d_in[30];
  float* out = (float*)d_out;

  float* ws = (float*)d_ws;
  float* W0 = ws;              // ph -> trp -> anchor_map
  float* W1 = W0 + SZ;         // delta -> transition
  float* W2 = W1 + SZ;         // locg/trg -> h1 (2*SZ) -> fused
  float* W3 = W2 + 2 * SZ;     // local
  float* sal = W3 + SZ;
  float* attout = sal + BTN;
  float* dppart = attout + (size_t)Bb * KK * Tt * Aa;
  float* appart = dppart + (size_t)BT * Aa;
  float* gw = appart + (size_t)Bb * KK * Aa;
  float* fmean = gw + (size_t)Bb * 3 * Aa;
  double* sal64 = (double*)(fmean + (size_t)BT * Aa);  // BT*NCAND doubles
  int* cand = (int*)(sal64 + (size_t)BT * NCAND);      // BT*NCAND ints
  int* idx = cand + (size_t)BT * NCAND;                // BT*KK ints

  // 1. ph = patch @ down_w.T + down_b
  gemm_nt<1, 1, 0><<<dim3(784, 3), 256, 0, stream>>>(
      x, down_w, down_b, W0, nullptr, BTN, Aa, Cc);
  // 2. delta + dp partials
  delta_kernel<<<BT, Aa, 0, stream>>>(W0, W1, dppart);
  // 3. saliency: fp32 candidates -> f64 refine -> exact top-8
  sal_kernel<<<BTN / 4, 256, 0, stream>>>(W1, sal);
  topcand_kernel<<<BT, 64, 0, stream>>>(sal, cand);
  refine_kernel<<<dim3(BT, 2), 192, 0, stream>>>(x, down_w, cand, sal64);
  select_kernel<<<BT, 64, 0, stream>>>(sal64, cand, idx);
  // 4. anchor attention
  attn_kernel<<<Bb * KK, 256, 0, stream>>>(
      W0, W1, idx, attn_in_w, attn_in_b, attn_out_w, attn_out_b, aproj_w,
      aproj_b, attout, appart);
  // 5. local branch
  conv2d_kernel<<<(unsigned)(SZ / 256), 256, 0, stream>>>(W0, ldw_w, W2);
  gemm_nt<0, 0, 0><<<dim3(784, 3), 256, 0, stream>>>(
      W2, lpw_w, nullptr, W3, nullptr, BTN, Aa, Aa);
  ln_kernel<<<BTN / 4, 256, 0, stream>>>(W3, lnorm_g, lnorm_b);
  // 6. transition branch
  conv1d_kernel<<<(unsigned)(SZ / 256), 256, 0, stream>>>(W1, tdw_w, W2);
  gemm_nt<0, 0, 0><<<dim3(784, 3), 256, 0, stream>>>(
      W2, tpw_w, nullptr, W0, nullptr, BTN, Aa, Aa);
  gemm_nt<0, 1, 1><<<dim3(784, 6), 256, 0, stream>>>(
      W0, tmlp_w1, tmlp_b1, W2, nullptr, BTN, 2 * Aa, Aa);
  gemm_nt<0, 1, 0><<<dim3(784, 3), 256, 0, stream>>>(
      W2, tmlp_w2, tmlp_b2, W1, nullptr, BTN, Aa, 2 * Aa);
  ln_kernel<<<BTN / 4, 256, 0, stream>>>(W1, tnorm_g, tnorm_b);
  // 7. anchor map
  hipMemsetAsync(W0, 0, SZ * sizeof(float), stream);
  scatter_kernel<<<BT, 256, 0, stream>>>(attout, idx, W0);
  ln_kernel<<<BTN / 4, 256, 0, stream>>>(W0, anorm_g, anorm_b);
  // 8. gate
  gate_kernel<<<Bb, Aa, 0, stream>>>(dppart, appart, gate_w1, gate_b1,
                                     gate_w2, gate_b2, gw);
  // 9. fuse + output projections
  fused_kernel<<<BT, Aa, 0, stream>>>(W3, W1, W0, gw, W2, fmean);
  gemm_nt<0, 1, 2><<<dim3(784, 12), 256, 0, stream>>>(
      W2, up_w, up_b, out, x, BTN, Cc, Aa);
  cls_kernel<<<BT, 256, 0, stream>>>(fmean, cls_w, cls_b, x, out);
}

// Round 3
// 1193.521 us; speedup vs baseline: 1.2285x; 1.2285x over previous
//
#include <hip/hip_runtime.h>
#include <math.h>

// ---- fixed problem dims ----
constexpr int Bb  = 16;
constexpr int Tt  = 16;
constexpr int Nn  = 196;   // patches (14x14)
constexpr int Cc  = 768;
constexpr int Aa  = 192;
constexpr int KK  = 8;     // TOPK
constexpr int NCAND = 16;  // fp32 candidates refined in f64
constexpr int BT  = Bb * Tt;            // 256
constexpr int BTN = BT * Nn;            // 50176
constexpr int BKT = Bb * KK * Tt;       // 2048 anchor-token rows
constexpr size_t SZ = (size_t)BTN * Aa; // 9,633,792 floats

static __device__ __forceinline__ float gelu_f(float x) {
  return 0.5f * x * (1.0f + erff(x * 0.7071067811865476f));
}

// ============================================================
// Generic fp32 GEMM: C[m,n] = sum_k A[m,k] * W[n,k] (+bias) (+epilogue)
// ============================================================
template <int ROWMAP, int BIAS, int EPI>
__global__ __launch_bounds__(256) void gemm_nt(
    const float* __restrict__ Ain, const float* __restrict__ W,
    const float* __restrict__ bias, float* __restrict__ Cout,
    const float* __restrict__ resid, int M, int Nc, int K) {
  __shared__ float As[16][68];
  __shared__ float Ws[16][68];
  const int tid = threadIdx.x;
  const int tx = tid & 15, ty = tid >> 4;
  const int row0 = blockIdx.x * 64;
  const int col0 = blockIdx.y * 64;
  const int lm = tid >> 2;         // 0..63
  const int lk = (tid & 3) << 2;   // 0,4,8,12

  const float* Arow;
  {
    int r = row0 + lm;
    if (ROWMAP) {
      int bt = r / Nn;
      int n = r - bt * Nn;
      Arow = Ain + (size_t)(bt * (Nn + 1) + 1 + n) * K;
    } else {
      Arow = Ain + (size_t)r * K;
    }
  }
  const float* Wrow = W + (size_t)(col0 + lm) * K;

  float acc[4][4] = {};
  for (int k0 = 0; k0 < K; k0 += 16) {
    float4 av = *(const float4*)(Arow + k0 + lk);
    float4 wv = *(const float4*)(Wrow + k0 + lk);
    As[lk + 0][lm] = av.x; As[lk + 1][lm] = av.y;
    As[lk + 2][lm] = av.z; As[lk + 3][lm] = av.w;
    Ws[lk + 0][lm] = wv.x; Ws[lk + 1][lm] = wv.y;
    Ws[lk + 2][lm] = wv.z; Ws[lk + 3][lm] = wv.w;
    __syncthreads();
#pragma unroll
    for (int kk = 0; kk < 16; ++kk) {
      float4 af = *(const float4*)&As[kk][ty * 4];
      float4 wf = *(const float4*)&Ws[kk][tx * 4];
      acc[0][0] = fmaf(af.x, wf.x, acc[0][0]);
      acc[0][1] = fmaf(af.x, wf.y, acc[0][1]);
      acc[0][2] = fmaf(af.x, wf.z, acc[0][2]);
      acc[0][3] = fmaf(af.x, wf.w, acc[0][3]);
      acc[1][0] = fmaf(af.y, wf.x, acc[1][0]);
      acc[1][1] = fmaf(af.y, wf.y, acc[1][1]);
      acc[1][2] = fmaf(af.y, wf.z, acc[1][2]);
      acc[1][3] = fmaf(af.y, wf.w, acc[1][3]);
      acc[2][0] = fmaf(af.z, wf.x, acc[2][0]);
      acc[2][1] = fmaf(af.z, wf.y, acc[2][1]);
      acc[2][2] = fmaf(af.z, wf.z, acc[2][2]);
      acc[2][3] = fmaf(af.z, wf.w, acc[2][3]);
      acc[3][0] = fmaf(af.w, wf.x, acc[3][0]);
      acc[3][1] = fmaf(af.w, wf.y, acc[3][1]);
      acc[3][2] = fmaf(af.w, wf.z, acc[3][2]);
      acc[3][3] = fmaf(af.w, wf.w, acc[3][3]);
    }
    __syncthreads();
  }
#pragma unroll
  for (int i = 0; i < 4; ++i) {
    int r = row0 + ty * 4 + i;
#pragma unroll
    for (int j = 0; j < 4; ++j) {
      int c = col0 + tx * 4 + j;
      float v = acc[i][j];
      if (BIAS) v += bias[c];
      if (EPI == 1) v = gelu_f(v);
      if (EPI == 2) {
        int bt = r / Nn;
        int n = r - bt * Nn;
        size_t off = (size_t)(bt * (Nn + 1) + 1 + n) * Nc + c;
        Cout[off] = resid[off] + v;
      } else {
        Cout[(size_t)r * Nc + c] = v;
      }
    }
  }
}

// ============================================================
// delta + per-(b,t) |delta| partials
// ============================================================
__global__ void delta_kernel(const float* __restrict__ ph,
                             float* __restrict__ delta,
                             float* __restrict__ dppart) {
  int bt = blockIdx.x;
  int t = bt & 15;
  int a = threadIdx.x;
  const float* cur = ph + (size_t)bt * Nn * Aa + a;
  float* dl = delta + (size_t)bt * Nn * Aa + a;
  float acc = 0.f;
  if (t == 0) {
    for (int n = 0; n < Nn; ++n) dl[(size_t)n * Aa] = 0.f;
  } else {
    const float* prev = cur - (size_t)Nn * Aa;
    for (int n = 0; n < Nn; ++n) {
      float d = cur[(size_t)n * Aa] - prev[(size_t)n * Aa];
      dl[(size_t)n * Aa] = d;
      acc += fabsf(d);
    }
  }
  dppart[bt * Aa + a] = acc;
}

// sal[row] = mean_a |delta[row,a]| (fp32, candidate stage only)
__global__ void sal_kernel(const float* __restrict__ delta,
                           float* __restrict__ sal) {
  int row = blockIdx.x * 4 + (threadIdx.x >> 6);
  int lane = threadIdx.x & 63;
  const float* d = delta + (size_t)row * Aa;
  float s = fabsf(d[lane]) + fabsf(d[lane + 64]) + fabsf(d[lane + 128]);
#pragma unroll
  for (int off = 32; off > 0; off >>= 1) s += __shfl_xor(s, off, 64);
  if (lane == 0) sal[row] = s * (1.0f / 192.0f);
}

// ============================================================
// top-16 fp32 candidates per (b,t); descending val, ties -> smaller n
// ============================================================
__global__ void topcand_kernel(const float* __restrict__ sal,
                               int* __restrict__ cand) {
  int bt = blockIdx.x;
  int lane = threadIdx.x;
  unsigned long long key[4];
#pragma unroll
  for (int j = 0; j < 4; ++j) {
    int n = lane + 64 * j;
    if (n < Nn) {
      unsigned fb = __float_as_uint(sal[(size_t)bt * Nn + n]);
      key[j] = ((unsigned long long)fb << 32) |
               (unsigned long long)(0xFFFFFFFFu - (unsigned)n);
    } else {
      key[j] = 0ULL;
    }
  }
  for (int r = 0; r < NCAND; ++r) {
    unsigned long long m = key[0];
    if (key[1] > m) m = key[1];
    if (key[2] > m) m = key[2];
    if (key[3] > m) m = key[3];
#pragma unroll
    for (int off = 32; off > 0; off >>= 1) {
      unsigned long long o = __shfl_xor(m, off, 64);
      if (o > m) m = o;
    }
    if (lane == 0)
      cand[bt * NCAND + r] = (int)(0xFFFFFFFFu - (unsigned)(m & 0xFFFFFFFFull));
#pragma unroll
    for (int j = 0; j < 4; ++j)
      if (key[j] == m) key[j] = 0ULL;
  }
}

// ============================================================
// f64 refine: sal64 = mean_a |sum_c (x_t - x_{t-1})[n,c] * down_w[a,c]|
// ============================================================
__global__ __launch_bounds__(192) void refine_kernel(
    const float* __restrict__ x, const float* __restrict__ down_w,
    const int* __restrict__ cand, double* __restrict__ sal64) {
  int bt = blockIdx.x;
  int grp = blockIdx.y;
  int t = bt & 15;
  int a = threadIdx.x;
  if (t == 0) {
    if (a < 8) sal64[bt * NCAND + grp * 8 + a] = 0.0;
    return;
  }
  __shared__ double sdiff[8][Cc];
  __shared__ double sabs[8][Aa];
  const float* xt = x + (size_t)bt * (Nn + 1) * Cc;
  const float* xp = xt - (size_t)(Nn + 1) * Cc;
  for (int g = 0; g < 8; ++g) {
    int n = cand[bt * NCAND + grp * 8 + g];
    const float* rt = xt + (size_t)(1 + n) * Cc;
    const float* rp = xp + (size_t)(1 + n) * Cc;
    for (int c = a; c < Cc; c += 192)
      sdiff[g][c] = (double)rt[c] - (double)rp[c];
  }
  __syncthreads();
  double acc[8] = {};
  const float* wrow = down_w + (size_t)a * Cc;
  for (int c0 = 0; c0 < Cc; c0 += 4) {
    float4 w4 = *(const float4*)(wrow + c0);
#pragma unroll
    for (int g = 0; g < 8; ++g) {
      acc[g] += (double)w4.x * sdiff[g][c0] + (double)w4.y * sdiff[g][c0 + 1] +
                (double)w4.z * sdiff[g][c0 + 2] +
                (double)w4.w * sdiff[g][c0 + 3];
    }
  }
#pragma unroll
  for (int g = 0; g < 8; ++g) sabs[g][a] = fabs(acc[g]);
  __syncthreads();
  if (a < 8) {
    double s = 0.0;
    for (int i = 0; i < Aa; ++i) s += sabs[a][i];
    sal64[bt * NCAND + grp * 8 + a] = s * (1.0 / 192.0);
  }
}

// final top-8 by (sal64 desc, n asc)
__global__ void select_kernel(const double* __restrict__ sal64,
                              const int* __restrict__ cand,
                              int* __restrict__ idx) {
  int bt = blockIdx.x;
  int t = bt & 15;
  if (threadIdx.x != 0) return;
  if (t == 0) {
    for (int r = 0; r < KK; ++r) idx[bt * KK + r] = r;
    return;
  }
  double v[NCAND];
  int nn[NCAND];
  bool used[NCAND];
  for (int i = 0; i < NCAND; ++i) {
    v[i] = sal64[bt * NCAND + i];
    nn[i] = cand[bt * NCAND + i];
    used[i] = false;
  }
  for (int r = 0; r < KK; ++r) {
    int best = -1;
    for (int i = 0; i < NCAND; ++i) {
      if (used[i]) continue;
      if (best < 0 || v[i] > v[best] ||
          (v[i] == v[best] && nn[i] < nn[best]))
        best = i;
    }
    used[best] = true;
    idx[bt * KK + r] = nn[best];
  }
}

// ============================================================
// anchor attention, restructured: gather -> GEMM qkv -> core -> GEMMs
// ============================================================
// tok[(b*KK+k)*16+t, a] = (ph+delta)[b,t,idx[b,t,k],a]
__global__ void gather_kernel(const float* __restrict__ ph,
                              const float* __restrict__ delta,
                              const int* __restrict__ idx,
                              float* __restrict__ tok) {
  int row = blockIdx.x;  // (b*KK+k)*16+t
  int t = row & 15;
  int bk = row >> 4;
  int b = bk >> 3, k = bk & 7;
  int a = threadIdx.x;
  int n = idx[(b * 16 + t) * KK + k];
  size_t off = ((size_t)(b * 16 + t) * Nn + n) * Aa + a;
  tok[(size_t)row * Aa + a] = ph[off] + delta[off];
}

// scores + softmax + PV for one (b,k) block; qkv rows are [q|k|v] of 576
__global__ __launch_bounds__(256) void attn_core(
    const float* __restrict__ qkv, float* __restrict__ o) {
  constexpr int P = 580;  // LDS pitch: bank stride 4 -> worst 2-way (free)
  __shared__ float sq[16 * P];
  __shared__ float ssc[4][16][17];
  int bk = blockIdx.x;
  int tid = threadIdx.x;
  const float* src = qkv + (size_t)bk * 16 * 576;
  for (int e = tid; e < 16 * 144; e += 256) {
    int r = e / 144, c4 = e % 144;
    float4 v = *(const float4*)(src + r * 576 + c4 * 4);
    *(float4*)(&sq[r * P + c4 * 4]) = v;
  }
  __syncthreads();
  int h = tid >> 6, lane = tid & 63;
#pragma unroll
  for (int s4 = 0; s4 < 4; ++s4) {
    int e = lane + 64 * s4;
    int i = e >> 4, j = e & 15;
    const float* q = sq + i * P + h * 48;
    const float* k2 = sq + j * P + 192 + h * 48;
    float s = 0.f;
#pragma unroll
    for (int d = 0; d < 48; ++d) s = fmaf(q[d], k2[d], s);
    ssc[h][i][j] = s * 0.14433756729740643f;  // 1/sqrt(48)
  }
  __syncthreads();
  if (lane < 16) {
    float* r = ssc[h][lane];
    float mx = r[0];
    for (int j = 1; j < 16; ++j) mx = fmaxf(mx, r[j]);
    float sum = 0.f;
    for (int j = 0; j < 16; ++j) {
      float ev = expf(r[j] - mx);
      r[j] = ev;
      sum += ev;
    }
    float inv = 1.0f / sum;
    for (int j = 0; j < 16; ++j) r[j] *= inv;
  }
  __syncthreads();
#pragma unroll
  for (int s4 = 0; s4 < 12; ++s4) {
    int e = lane + 64 * s4;
    int i = e / 48, d = e - i * 48;
    float s = 0.f;
#pragma unroll
    for (int j = 0; j < 16; ++j)
      s = fmaf(ssc[h][i][j], sq[j * P + 384 + h * 48 + d], s);
    o[((size_t)bk * 16 + i) * 192 + h * 48 + d] = s;
  }
}

// appart[bk,a] = sum_t attout[bk,t,a]
__global__ void appart_kernel(const float* __restrict__ attout,
                              float* __restrict__ appart) {
  int bk = blockIdx.x;
  int a = threadIdx.x;
  float s = 0.f;
  for (int t = 0; t < Tt; ++t)
    s += attout[((size_t)bk * Tt + t) * Aa + a];
  appart[bk * Aa + a] = s;
}

// depthwise 3x3 SAME conv over 14x14 + gelu
__global__ void conv2d_kernel(const float* __restrict__ ph,
                              const float* __restrict__ ldw,
                              float* __restrict__ og) {
  size_t e = (size_t)blockIdx.x * 256 + threadIdx.x;
  int a = (int)(e % Aa);
  size_t r = e / Aa;
  int n = (int)(r % Nn);
  int bt = (int)(r / Nn);
  int y = n / 14, x = n % 14;
  const float* base = ph + (size_t)bt * Nn * Aa + a;
  const float* w = ldw + a * 9;
  float s = 0.f;
#pragma unroll
  for (int dy = -1; dy <= 1; ++dy) {
    int yy = y + dy;
    if (yy < 0 || yy >= 14) continue;
#pragma unroll
    for (int dx = -1; dx <= 1; ++dx) {
      int xc = x + dx;
      if (xc < 0 || xc >= 14) continue;
      s = fmaf(base[(size_t)(yy * 14 + xc) * Aa], w[(dy + 1) * 3 + (dx + 1)], s);
    }
  }
  og[e] = gelu_f(s);
}

// depthwise k=3 SAME conv over t + gelu
__global__ void conv1d_kernel(const float* __restrict__ delta,
                              const float* __restrict__ tdw,
                              float* __restrict__ og) {
  size_t e = (size_t)blockIdx.x * 256 + threadIdx.x;
  int a = (int)(e % Aa);
  size_t r = e / Aa;
  int n = (int)(r % Nn);
  int bt = (int)(r / Nn);
  int t = bt & 15, b = bt >> 4;
  const float* w = tdw + a * 3;
  float s = 0.f;
#pragma unroll
  for (int j = 0; j < 3; ++j) {
    int tt = t + j - 1;
    if (tt >= 0 && tt < Tt)
      s = fmaf(delta[((size_t)(b * Tt + tt) * Nn + n) * Aa + a], w[j], s);
  }
  og[e] = gelu_f(s);
}

// in-place LayerNorm over last dim (192); one wave per row
__global__ void ln_kernel(float* __restrict__ buf, const float* __restrict__ g,
                          const float* __restrict__ bb) {
  size_t row = (size_t)blockIdx.x * 4 + (threadIdx.x >> 6);
  int lane = threadIdx.x & 63;
  float* p = buf + row * Aa;
  float v0 = p[lane], v1 = p[lane + 64], v2 = p[lane + 128];
  float s = v0 + v1 + v2;
#pragma unroll
  for (int off = 32; off > 0; off >>= 1) s += __shfl_xor(s, off, 64);
  float m = s * (1.0f / 192.0f);
  float d0 = v0 - m, d1 = v1 - m, d2 = v2 - m;
  float ss = d0 * d0 + d1 * d1 + d2 * d2;
#pragma unroll
  for (int off = 32; off > 0; off >>= 1) ss += __shfl_xor(ss, off, 64);
  float inv = rsqrtf(ss * (1.0f / 192.0f) + 1e-5f);
  p[lane] = d0 * inv * g[lane] + bb[lane];
  p[lane + 64] = d1 * inv * g[lane + 64] + bb[lane + 64];
  p[lane + 128] = d2 * inv * g[lane + 128] + bb[lane + 128];
}

// scatter anchor_tok into zeroed anchor_map
__global__ void scatter_kernel(const float* __restrict__ attout,
                               const int* __restrict__ idx,
                               float* __restrict__ amap) {
  int bt = blockIdx.x;
  int b = bt >> 4, t = bt & 15;
  for (int e = threadIdx.x; e < KK * Aa; e += 256) {
    int k = e / Aa, a = e % Aa;
    int n = idx[bt * KK + k];
    amap[((size_t)bt * Nn + n) * Aa + a] =
        attout[((size_t)(b * KK + k) * Tt + t) * Aa + a];
  }
}

// gate MLP + 3-way softmax; one block per b, 192 threads
__global__ void gate_kernel(const float* __restrict__ dppart,
                            const float* __restrict__ appart,
                            const float* __restrict__ w1,
                            const float* __restrict__ b1,
                            const float* __restrict__ w2,
                            const float* __restrict__ b2,
                            float* __restrict__ gw) {
  int b = blockIdx.x;
  __shared__ float sg[2 * Aa];
  __shared__ float sh[Aa];
  int tid = threadIdx.x;
  {
    float d = 0.f;
    for (int t2 = 0; t2 < Tt; ++t2) d += dppart[(b * Tt + t2) * Aa + tid];
    sg[tid] = d * (1.0f / 3136.0f);
    float a = 0.f;
    for (int k2 = 0; k2 < KK; ++k2) a += appart[(b * KK + k2) * Aa + tid];
    sg[Aa + tid] = a * (1.0f / 128.0f);
  }
  __syncthreads();
  {
    const float* w = w1 + (size_t)tid * 2 * Aa;
    float s = b1[tid];
#pragma unroll 8
    for (int j = 0; j < 2 * Aa; ++j) s = fmaf(sg[j], w[j], s);
    sh[tid] = gelu_f(s);
  }
  __syncthreads();
  float v[3];
#pragma unroll
  for (int i = 0; i < 3; ++i) {
    const float* w = w2 + (size_t)(i * Aa + tid) * Aa;
    float s = b2[i * Aa + tid];
#pragma unroll 8
    for (int j = 0; j < Aa; ++j) s = fmaf(sh[j], w[j], s);
    v[i] = s;
  }
  float mx = fmaxf(v[0], fmaxf(v[1], v[2]));
  float e0 = expf(v[0] - mx), e1 = expf(v[1] - mx), e2 = expf(v[2] - mx);
  float inv = 1.0f / (e0 + e1 + e2);
  gw[(b * 3 + 0) * Aa + tid] = e0 * inv;
  gw[(b * 3 + 1) * Aa + tid] = e1 * inv;
  gw[(b * 3 + 2) * Aa + tid] = e2 * inv;
}

// fused = gw0*local + gw1*trans + gw2*amap; fmean[bt,a] = sum_n fused
__global__ void fused_kernel(const float* __restrict__ local,
                             const float* __restrict__ trans,
                             const float* __restrict__ amap,
                             const float* __restrict__ gw,
                             float* __restrict__ fused,
                             float* __restrict__ fmean) {
  int bt = blockIdx.x;
  int b = bt >> 4;
  int a = threadIdx.x;
  float g0 = gw[(b * 3 + 0) * Aa + a];
  float g1 = gw[(b * 3 + 1) * Aa + a];
  float g2 = gw[(b * 3 + 2) * Aa + a];
  size_t base = (size_t)bt * Nn * Aa + a;
  float acc = 0.f;
  for (int n = 0; n < Nn; ++n) {
    size_t o = base + (size_t)n * Aa;
    float f = g0 * local[o] + g1 * trans[o] + g2 * amap[o];
    fused[o] = f;
    acc += f;
  }
  fmean[bt * Aa + a] = acc;
}

// cls_out = cls_tok + (mean_n fused) @ cls_w.T + cls_b
__global__ void cls_kernel(const float* __restrict__ fmean,
                           const float* __restrict__ cw,
                           const float* __restrict__ cb,
                           const float* __restrict__ x,
                           float* __restrict__ out) {
  int bt = blockIdx.x;
  __shared__ float fm[Aa];
  int tid = threadIdx.x;
  if (tid < Aa) fm[tid] = fmean[bt * Aa + tid] * (1.0f / 196.0f);
  __syncthreads();
  for (int c = tid; c < Cc; c += 256) {
    const float* w = cw + (size_t)c * Aa;
    float s = cb[c];
#pragma unroll 8
    for (int a = 0; a < Aa; ++a) s = fmaf(fm[a], w[a], s);
    size_t off = (size_t)bt * (Nn + 1) * Cc + c;
    out[off] = x[off] + s;
  }
}

// ============================================================
extern "C" void kernel_launch(void* const* d_in, const int* in_sizes, int n_in,
                              void* d_out, int out_size, void* d_ws,
                              size_t ws_size, hipStream_t stream) {
  const float* x = (const float*)d_in[0];
  const float* down_w = (const float*)d_in[1];
  const float* down_b = (const float*)d_in[2];
  const float* ldw_w = (const float*)d_in[3];
  const float* lpw_w = (const float*)d_in[4];
  const float* lnorm_g = (const float*)d_in[5];
  const float* lnorm_b = (const float*)d_in[6];
  const float* tdw_w = (const float*)d_in[7];
  const float* tpw_w = (const float*)d_in[8];
  const float* tmlp_w1 = (const float*)d_in[9];
  const float* tmlp_b1 = (const float*)d_in[10];
  const float* tmlp_w2 = (const float*)d_in[11];
  const float* tmlp_b2 = (const float*)d_in[12];
  const float* tnorm_g = (const float*)d_in[13];
  const float* tnorm_b = (const float*)d_in[14];
  const float* attn_in_w = (const float*)d_in[15];
  const float* attn_in_b = (const float*)d_in[16];
  const float* attn_out_w = (const float*)d_in[17];
  const float* attn_out_b = (const float*)d_in[18];
  const float* aproj_w = (const float*)d_in[19];
  const float* aproj_b = (const float*)d_in[20];
  const float* anorm_g = (const float*)d_in[21];
  const float* anorm_b = (const float*)d_in[22];
  const float* gate_w1 = (const float*)d_in[23];
  const float* gate_b1 = (const float*)d_in[24];
  const float* gate_w2 = (const float*)d_in[25];
  const float* gate_b2 = (const float*)d_in[26];
  const float* up_w = (const float*)d_in[27];
  const float* up_b = (const float*)d_in[28];
  const float* cls_w = (const float*)d_in[29];
  const float* cls_b = (const float*)d_in[30];
  float* out = (float*)d_out;

  float* ws = (float*)d_ws;
  float* W0 = ws;              // ph -> trp -> anchor_map
  float* W1 = W0 + SZ;         // delta -> transition
  float* W2 = W1 + SZ;         // attn scratch -> locg/trg -> h1 -> fused
  float* W3 = W2 + 2 * SZ;     // local
  float* sal = W3 + SZ;
  float* attout = sal + BTN;
  float* dppart = attout + (size_t)BKT * Aa;
  float* appart = dppart + (size_t)BT * Aa;
  float* gw = appart + (size_t)Bb * KK * Aa;
  float* fmean = gw + (size_t)Bb * 3 * Aa;
  double* sal64 = (double*)(fmean + (size_t)BT * Aa);  // BT*NCAND doubles
  int* cand = (int*)(sal64 + (size_t)BT * NCAND);      // BT*NCAND ints
  int* idx = cand + (size_t)BT * NCAND;                // BT*KK ints

  // attn-phase scratch lives inside W2 (dead until conv2d)
  float* tok   = W2;                       // 2048*192
  float* qkvb  = tok + (size_t)BKT * Aa;   // 2048*576
  float* obuf  = qkvb + (size_t)BKT * 3 * Aa;  // 2048*192
  float* proj1 = obuf + (size_t)BKT * Aa;  // 2048*192

  // 1. ph = patch @ down_w.T + down_b
  gemm_nt<1, 1, 0><<<dim3(784, 3), 256, 0, stream>>>(
      x, down_w, down_b, W0, nullptr, BTN, Aa, Cc);
  // 2. delta + dp partials
  delta_kernel<<<BT, Aa, 0, stream>>>(W0, W1, dppart);
  // 3. saliency: fp32 candidates -> f64 refine -> exact top-8
  sal_kernel<<<BTN / 4, 256, 0, stream>>>(W1, sal);
  topcand_kernel<<<BT, 64, 0, stream>>>(sal, cand);
  refine_kernel<<<dim3(BT, 2), 192, 0, stream>>>(x, down_w, cand, sal64);
  select_kernel<<<BT, 64, 0, stream>>>(sal64, cand, idx);
  // 4. anchor attention (GEMM-structured)
  gather_kernel<<<BKT, Aa, 0, stream>>>(W0, W1, idx, tok);
  gemm_nt<0, 1, 0><<<dim3(32, 9), 256, 0, stream>>>(
      tok, attn_in_w, attn_in_b, qkvb, nullptr, BKT, 3 * Aa, Aa);
  attn_core<<<Bb * KK, 256, 0, stream>>>(qkvb, obuf);
  gemm_nt<0, 1, 0><<<dim3(32, 3), 256, 0, stream>>>(
      obuf, attn_out_w, attn_out_b, proj1, nullptr, BKT, Aa, Aa);
  gemm_nt<0, 1, 0><<<dim3(32, 3), 256, 0, stream>>>(
      proj1, aproj_w, aproj_b, attout, nullptr, BKT, Aa, Aa);
  appart_kernel<<<Bb * KK, Aa, 0, stream>>>(attout, appart);
  // 5. local branch
  conv2d_kernel<<<(unsigned)(SZ / 256), 256, 0, stream>>>(W0, ldw_w, W2);
  gemm_nt<0, 0, 0><<<dim3(784, 3), 256, 0, stream>>>(
      W2, lpw_w, nullptr, W3, nullptr, BTN, Aa, Aa);
  ln_kernel<<<BTN / 4, 256, 0, stream>>>(W3, lnorm_g, lnorm_b);
  // 6. transition branch
  conv1d_kernel<<<(unsigned)(SZ / 256), 256, 0, stream>>>(W1, tdw_w, W2);
  gemm_nt<0, 0, 0><<<dim3(784, 3), 256, 0, stream>>>(
      W2, tpw_w, nullptr, W0, nullptr, BTN, Aa, Aa);
  gemm_nt<0, 1, 1><<<dim3(784, 6), 256, 0, stream>>>(
      W0, tmlp_w1, tmlp_b1, W2, nullptr, BTN, 2 * Aa, Aa);
  gemm_nt<0, 1, 0><<<dim3(784, 3), 256, 0, stream>>>(
      W2, tmlp_w2, tmlp_b2, W1, nullptr, BTN, Aa, 2 * Aa);
  ln_kernel<<<BTN / 4, 256, 0, stream>>>(W1, tnorm_g, tnorm_b);
  // 7. anchor map
  hipMemsetAsync(W0, 0, SZ * sizeof(float), stream);
  scatter_kernel<<<BT, 256, 0, stream>>>(attout, idx, W0);
  ln_kernel<<<BTN / 4, 256, 0, stream>>>(W0, anorm_g, anorm_b);
  // 8. gate
  gate_kernel<<<Bb, Aa, 0, stream>>>(dppart, appart, gate_w1, gate_b1,
                                     gate_w2, gate_b2, gw);
  // 9. fuse + output projections
  fused_kernel<<<BT, Aa, 0, stream>>>(W3, W1, W0, gw, W2, fmean);
  gemm_nt<0, 1, 2><<<dim3(784, 12), 256, 0, stream>>>(
      W2, up_w, up_b, out, x, BTN, Cc, Aa);
  cls_kernel<<<BT, 256, 0, stream>>>(fmean, cls_w, cls_b, x, out);
}

// Round 4
// 724.903 us; speedup vs baseline: 2.0226x; 1.6465x over previous
//
#include <hip/hip_runtime.h>
#include <math.h>

// ---- fixed problem dims ----
constexpr int Bb  = 16;
constexpr int Tt  = 16;
constexpr int Nn  = 196;   // patches (14x14)
constexpr int Cc  = 768;
constexpr int Aa  = 192;
constexpr int KK  = 8;     // TOPK
constexpr int NCAND = 16;  // fp32 candidates refined in f64
constexpr int BT  = Bb * Tt;            // 256
constexpr int BTN = BT * Nn;            // 50176
constexpr int BKT = Bb * KK * Tt;       // 2048 anchor-token rows
constexpr size_t SZ = (size_t)BTN * Aa; // 9,633,792 floats

static __device__ __forceinline__ float gelu_f(float x) {
  return 0.5f * x * (1.0f + erff(x * 0.7071067811865476f));
}

typedef __attribute__((ext_vector_type(8))) short bf16x8;
typedef __attribute__((ext_vector_type(4))) float f32x4;
typedef __attribute__((ext_vector_type(4))) unsigned short u16x4;

static __device__ __forceinline__ unsigned short f2bf(float f) {
  unsigned u = __float_as_uint(f);
  u += 0x7FFFu + ((u >> 16) & 1u);  // round-to-nearest-even
  return (unsigned short)(u >> 16);
}

// ============================================================
// bf16 MFMA GEMM: C[m,n] = sum_k A[m,k]*W[n,k] (+bias)(+epilogue)
// A fp32 (row-major MxK, optional ROWMAP into x's N+1 layout), W fp32 NxK.
// Staged to LDS as bf16; fp32 accumulate via mfma_f32_16x16x32_bf16.
// BM=128 BN=64 BK=32, 256 thr = 4 waves (2x2), wave tile 64x32.
// EPI: 0 plain, 1 gelu, 2 mapped residual (up-proj)
// ============================================================
template <int ROWMAP, int BIAS, int EPI>
__global__ __launch_bounds__(256) void gemm_mfma(
    const float* __restrict__ Ain, const float* __restrict__ W,
    const float* __restrict__ bias, float* __restrict__ Cout,
    const float* __restrict__ resid, int M, int Nc, int K) {
  constexpr int PIT = 40;  // bf16 pitch (32 + 8 pad) -> 2-way bank max (free)
  __shared__ unsigned short As[2][128 * PIT];
  __shared__ unsigned short Bs[2][64 * PIT];
  const int tid = threadIdx.x;
  const int row0 = blockIdx.x * 128;
  const int col0 = blockIdx.y * 64;
  const int wid = tid >> 6;
  const int lane = tid & 63;
  const int wr = wid >> 1;       // 0..1 -> +64 rows
  const int wc = wid & 1;        // 0..1 -> +32 cols
  const int l15 = lane & 15;
  const int kgrp = lane >> 4;    // 0..3

  // staging: quad = k-float4 index, srow = row within 32-row pass
  const int quad = tid & 7;
  const int srow = tid >> 3;     // 0..31

  const int nsteps = K >> 5;

  const float* arowp[4];
#pragma unroll
  for (int p = 0; p < 4; ++p) {
    int r = row0 + srow + 32 * p;
    if (ROWMAP) {
      int bt = r / Nn;
      int n = r - bt * Nn;
      arowp[p] = Ain + (size_t)(bt * (Nn + 1) + 1 + n) * K;
    } else {
      arowp[p] = Ain + (size_t)r * K;
    }
  }
  const float* browp[2];
#pragma unroll
  for (int p = 0; p < 2; ++p)
    browp[p] = W + (size_t)(col0 + srow + 32 * p) * K;

  f32x4 acc[4][2];
#pragma unroll
  for (int i = 0; i < 4; ++i)
#pragma unroll
    for (int j = 0; j < 2; ++j) acc[i][j] = (f32x4){0.f, 0.f, 0.f, 0.f};

  float4 apre[4], bpre[2];
  // prologue: load k-tile 0, write LDS buf 0
#pragma unroll
  for (int p = 0; p < 4; ++p) apre[p] = *(const float4*)(arowp[p] + quad * 4);
#pragma unroll
  for (int p = 0; p < 2; ++p) bpre[p] = *(const float4*)(browp[p] + quad * 4);
#pragma unroll
  for (int p = 0; p < 4; ++p) {
    u16x4 b = {f2bf(apre[p].x), f2bf(apre[p].y), f2bf(apre[p].z), f2bf(apre[p].w)};
    *(u16x4*)&As[0][(srow + 32 * p) * PIT + quad * 4] = b;
  }
#pragma unroll
  for (int p = 0; p < 2; ++p) {
    u16x4 b = {f2bf(bpre[p].x), f2bf(bpre[p].y), f2bf(bpre[p].z), f2bf(bpre[p].w)};
    *(u16x4*)&Bs[0][(srow + 32 * p) * PIT + quad * 4] = b;
  }
  __syncthreads();

  int cur = 0;
  for (int step = 0; step < nsteps; ++step) {
    const bool pref = (step + 1 < nsteps);
    if (pref) {
      int k0 = (step + 1) << 5;
#pragma unroll
      for (int p = 0; p < 4; ++p)
        apre[p] = *(const float4*)(arowp[p] + k0 + quad * 4);
#pragma unroll
      for (int p = 0; p < 2; ++p)
        bpre[p] = *(const float4*)(browp[p] + k0 + quad * 4);
    }
    // compute on cur
    bf16x8 af[4], bfv[2];
#pragma unroll
    for (int fm = 0; fm < 4; ++fm)
      af[fm] = *(const bf16x8*)&As[cur][(wr * 64 + fm * 16 + l15) * PIT + kgrp * 8];
#pragma unroll
    for (int fn = 0; fn < 2; ++fn)
      bfv[fn] = *(const bf16x8*)&Bs[cur][(wc * 32 + fn * 16 + l15) * PIT + kgrp * 8];
#pragma unroll
    for (int fm = 0; fm < 4; ++fm)
#pragma unroll
      for (int fn = 0; fn < 2; ++fn)
        acc[fm][fn] = __builtin_amdgcn_mfma_f32_16x16x32_bf16(
            af[fm], bfv[fn], acc[fm][fn], 0, 0, 0);
    if (pref) {
#pragma unroll
      for (int p = 0; p < 4; ++p) {
        u16x4 b = {f2bf(apre[p].x), f2bf(apre[p].y), f2bf(apre[p].z), f2bf(apre[p].w)};
        *(u16x4*)&As[cur ^ 1][(srow + 32 * p) * PIT + quad * 4] = b;
      }
#pragma unroll
      for (int p = 0; p < 2; ++p) {
        u16x4 b = {f2bf(bpre[p].x), f2bf(bpre[p].y), f2bf(bpre[p].z), f2bf(bpre[p].w)};
        *(u16x4*)&Bs[cur ^ 1][(srow + 32 * p) * PIT + quad * 4] = b;
      }
    }
    __syncthreads();
    cur ^= 1;
  }

  // epilogue: C/D layout col=lane&15, row=(lane>>4)*4+j
#pragma unroll
  for (int fm = 0; fm < 4; ++fm) {
    int rbase = row0 + wr * 64 + fm * 16 + kgrp * 4;
#pragma unroll
    for (int fn = 0; fn < 2; ++fn) {
      int c = col0 + wc * 32 + fn * 16 + l15;
      float bv = BIAS ? bias[c] : 0.f;
#pragma unroll
      for (int j = 0; j < 4; ++j) {
        int r = rbase + j;
        float v = acc[fm][fn][j] + bv;
        if (EPI == 1) v = gelu_f(v);
        if (EPI == 2) {
          int bt = r / Nn;
          int n = r - bt * Nn;
          size_t off = (size_t)(bt * (Nn + 1) + 1 + n) * Nc + c;
          Cout[off] = resid[off] + v;
        } else {
          Cout[(size_t)r * Nc + c] = v;
        }
      }
    }
  }
}

// ============================================================
// delta + per-(b,t) |delta| partials
// ============================================================
__global__ void delta_kernel(const float* __restrict__ ph,
                             float* __restrict__ delta,
                             float* __restrict__ dppart) {
  int bt = blockIdx.x;
  int t = bt & 15;
  int a = threadIdx.x;
  const float* cur = ph + (size_t)bt * Nn * Aa + a;
  float* dl = delta + (size_t)bt * Nn * Aa + a;
  float acc = 0.f;
  if (t == 0) {
    for (int n = 0; n < Nn; ++n) dl[(size_t)n * Aa] = 0.f;
  } else {
    const float* prev = cur - (size_t)Nn * Aa;
    for (int n = 0; n < Nn; ++n) {
      float d = cur[(size_t)n * Aa] - prev[(size_t)n * Aa];
      dl[(size_t)n * Aa] = d;
      acc += fabsf(d);
    }
  }
  dppart[bt * Aa + a] = acc;
}

// sal[row] = mean_a |delta[row,a]| (fp32, candidate stage only)
__global__ void sal_kernel(const float* __restrict__ delta,
                           float* __restrict__ sal) {
  int row = blockIdx.x * 4 + (threadIdx.x >> 6);
  int lane = threadIdx.x & 63;
  const float* d = delta + (size_t)row * Aa;
  float s = fabsf(d[lane]) + fabsf(d[lane + 64]) + fabsf(d[lane + 128]);
#pragma unroll
  for (int off = 32; off > 0; off >>= 1) s += __shfl_xor(s, off, 64);
  if (lane == 0) sal[row] = s * (1.0f / 192.0f);
}

// ============================================================
// top-16 fp32 candidates per (b,t); descending val, ties -> smaller n
// ============================================================
__global__ void topcand_kernel(const float* __restrict__ sal,
                               int* __restrict__ cand) {
  int bt = blockIdx.x;
  int lane = threadIdx.x;
  unsigned long long key[4];
#pragma unroll
  for (int j = 0; j < 4; ++j) {
    int n = lane + 64 * j;
    if (n < Nn) {
      unsigned fb = __float_as_uint(sal[(size_t)bt * Nn + n]);
      key[j] = ((unsigned long long)fb << 32) |
               (unsigned long long)(0xFFFFFFFFu - (unsigned)n);
    } else {
      key[j] = 0ULL;
    }
  }
  for (int r = 0; r < NCAND; ++r) {
    unsigned long long m = key[0];
    if (key[1] > m) m = key[1];
    if (key[2] > m) m = key[2];
    if (key[3] > m) m = key[3];
#pragma unroll
    for (int off = 32; off > 0; off >>= 1) {
      unsigned long long o = __shfl_xor(m, off, 64);
      if (o > m) m = o;
    }
    if (lane == 0)
      cand[bt * NCAND + r] = (int)(0xFFFFFFFFu - (unsigned)(m & 0xFFFFFFFFull));
#pragma unroll
    for (int j = 0; j < 4; ++j)
      if (key[j] == m) key[j] = 0ULL;
  }
}

// ============================================================
// f64 refine: sal64 = mean_a |sum_c (x_t - x_{t-1})[n,c] * down_w[a,c]|
// ============================================================
__global__ __launch_bounds__(192) void refine_kernel(
    const float* __restrict__ x, const float* __restrict__ down_w,
    const int* __restrict__ cand, double* __restrict__ sal64) {
  int bt = blockIdx.x;
  int grp = blockIdx.y;
  int t = bt & 15;
  int a = threadIdx.x;
  if (t == 0) {
    if (a < 8) sal64[bt * NCAND + grp * 8 + a] = 0.0;
    return;
  }
  __shared__ double sdiff[8][Cc];
  __shared__ double sabs[8][Aa];
  const float* xt = x + (size_t)bt * (Nn + 1) * Cc;
  const float* xp = xt - (size_t)(Nn + 1) * Cc;
  for (int g = 0; g < 8; ++g) {
    int n = cand[bt * NCAND + grp * 8 + g];
    const float* rt = xt + (size_t)(1 + n) * Cc;
    const float* rp = xp + (size_t)(1 + n) * Cc;
    for (int c = a; c < Cc; c += 192)
      sdiff[g][c] = (double)rt[c] - (double)rp[c];
  }
  __syncthreads();
  double acc[8] = {};
  const float* wrow = down_w + (size_t)a * Cc;
  for (int c0 = 0; c0 < Cc; c0 += 4) {
    float4 w4 = *(const float4*)(wrow + c0);
#pragma unroll
    for (int g = 0; g < 8; ++g) {
      acc[g] += (double)w4.x * sdiff[g][c0] + (double)w4.y * sdiff[g][c0 + 1] +
                (double)w4.z * sdiff[g][c0 + 2] +
                (double)w4.w * sdiff[g][c0 + 3];
    }
  }
#pragma unroll
  for (int g = 0; g < 8; ++g) sabs[g][a] = fabs(acc[g]);
  __syncthreads();
  if (a < 8) {
    double s = 0.0;
    for (int i = 0; i < Aa; ++i) s += sabs[a][i];
    sal64[bt * NCAND + grp * 8 + a] = s * (1.0 / 192.0);
  }
}

// final top-8 by (sal64 desc, n asc)
__global__ void select_kernel(const double* __restrict__ sal64,
                              const int* __restrict__ cand,
                              int* __restrict__ idx) {
  int bt = blockIdx.x;
  int t = bt & 15;
  if (threadIdx.x != 0) return;
  if (t == 0) {
    for (int r = 0; r < KK; ++r) idx[bt * KK + r] = r;
    return;
  }
  double v[NCAND];
  int nn[NCAND];
  bool used[NCAND];
  for (int i = 0; i < NCAND; ++i) {
    v[i] = sal64[bt * NCAND + i];
    nn[i] = cand[bt * NCAND + i];
    used[i] = false;
  }
  for (int r = 0; r < KK; ++r) {
    int best = -1;
    for (int i = 0; i < NCAND; ++i) {
      if (used[i]) continue;
      if (best < 0 || v[i] > v[best] ||
          (v[i] == v[best] && nn[i] < nn[best]))
        best = i;
    }
    used[best] = true;
    idx[bt * KK + r] = nn[best];
  }
}

// ============================================================
// anchor attention: gather -> GEMM qkv -> core -> GEMMs
// ============================================================
__global__ void gather_kernel(const float* __restrict__ ph,
                              const float* __restrict__ delta,
                              const int* __restrict__ idx,
                              float* __restrict__ tok) {
  int row = blockIdx.x;  // (b*KK+k)*16+t
  int t = row & 15;
  int bk = row >> 4;
  int b = bk >> 3, k = bk & 7;
  int a = threadIdx.x;
  int n = idx[(b * 16 + t) * KK + k];
  size_t off = ((size_t)(b * 16 + t) * Nn + n) * Aa + a;
  tok[(size_t)row * Aa + a] = ph[off] + delta[off];
}

// scores + softmax + PV for one (b,k) block; qkv rows are [q|k|v] of 576
__global__ __launch_bounds__(256) void attn_core(
    const float* __restrict__ qkv, float* __restrict__ o) {
  constexpr int P = 580;
  __shared__ float sq[16 * P];
  __shared__ float ssc[4][16][17];
  int bk = blockIdx.x;
  int tid = threadIdx.x;
  const float* src = qkv + (size_t)bk * 16 * 576;
  for (int e = tid; e < 16 * 144; e += 256) {
    int r = e / 144, c4 = e % 144;
    float4 v = *(const float4*)(src + r * 576 + c4 * 4);
    *(float4*)(&sq[r * P + c4 * 4]) = v;
  }
  __syncthreads();
  int h = tid >> 6, lane = tid & 63;
#pragma unroll
  for (int s4 = 0; s4 < 4; ++s4) {
    int e = lane + 64 * s4;
    int i = e >> 4, j = e & 15;
    const float* q = sq + i * P + h * 48;
    const float* k2 = sq + j * P + 192 + h * 48;
    float s = 0.f;
#pragma unroll
    for (int d = 0; d < 48; ++d) s = fmaf(q[d], k2[d], s);
    ssc[h][i][j] = s * 0.14433756729740643f;  // 1/sqrt(48)
  }
  __syncthreads();
  if (lane < 16) {
    float* r = ssc[h][lane];
    float mx = r[0];
    for (int j = 1; j < 16; ++j) mx = fmaxf(mx, r[j]);
    float sum = 0.f;
    for (int j = 0; j < 16; ++j) {
      float ev = expf(r[j] - mx);
      r[j] = ev;
      sum += ev;
    }
    float inv = 1.0f / sum;
    for (int j = 0; j < 16; ++j) r[j] *= inv;
  }
  __syncthreads();
#pragma unroll
  for (int s4 = 0; s4 < 12; ++s4) {
    int e = lane + 64 * s4;
    int i = e / 48, d = e - i * 48;
    float s = 0.f;
#pragma unroll
    for (int j = 0; j < 16; ++j)
      s = fmaf(ssc[h][i][j], sq[j * P + 384 + h * 48 + d], s);
    o[((size_t)bk * 16 + i) * 192 + h * 48 + d] = s;
  }
}

// appart[bk,a] = sum_t attout[bk,t,a]
__global__ void appart_kernel(const float* __restrict__ attout,
                              float* __restrict__ appart) {
  int bk = blockIdx.x;
  int a = threadIdx.x;
  float s = 0.f;
  for (int t = 0; t < Tt; ++t)
    s += attout[((size_t)bk * Tt + t) * Aa + a];
  appart[bk * Aa + a] = s;
}

// depthwise 3x3 SAME conv over 14x14 + gelu
__global__ void conv2d_kernel(const float* __restrict__ ph,
                              const float* __restrict__ ldw,
                              float* __restrict__ og) {
  size_t e = (size_t)blockIdx.x * 256 + threadIdx.x;
  int a = (int)(e % Aa);
  size_t r = e / Aa;
  int n = (int)(r % Nn);
  int bt = (int)(r / Nn);
  int y = n / 14, x = n % 14;
  const float* base = ph + (size_t)bt * Nn * Aa + a;
  const float* w = ldw + a * 9;
  float s = 0.f;
#pragma unroll
  for (int dy = -1; dy <= 1; ++dy) {
    int yy = y + dy;
    if (yy < 0 || yy >= 14) continue;
#pragma unroll
    for (int dx = -1; dx <= 1; ++dx) {
      int xc = x + dx;
      if (xc < 0 || xc >= 14) continue;
      s = fmaf(base[(size_t)(yy * 14 + xc) * Aa], w[(dy + 1) * 3 + (dx + 1)], s);
    }
  }
  og[e] = gelu_f(s);
}

// depthwise k=3 SAME conv over t + gelu
__global__ void conv1d_kernel(const float* __restrict__ delta,
                              const float* __restrict__ tdw,
                              float* __restrict__ og) {
  size_t e = (size_t)blockIdx.x * 256 + threadIdx.x;
  int a = (int)(e % Aa);
  size_t r = e / Aa;
  int n = (int)(r % Nn);
  int bt = (int)(r / Nn);
  int t = bt & 15, b = bt >> 4;
  const float* w = tdw + a * 3;
  float s = 0.f;
#pragma unroll
  for (int j = 0; j < 3; ++j) {
    int tt = t + j - 1;
    if (tt >= 0 && tt < Tt)
      s = fmaf(delta[((size_t)(b * Tt + tt) * Nn + n) * Aa + a], w[j], s);
  }
  og[e] = gelu_f(s);
}

// in-place LayerNorm over last dim (192); one wave per row
__global__ void ln_kernel(float* __restrict__ buf, const float* __restrict__ g,
                          const float* __restrict__ bb) {
  size_t row = (size_t)blockIdx.x * 4 + (threadIdx.x >> 6);
  int lane = threadIdx.x & 63;
  float* p = buf + row * Aa;
  float v0 = p[lane], v1 = p[lane + 64], v2 = p[lane + 128];
  float s = v0 + v1 + v2;
#pragma unroll
  for (int off = 32; off > 0; off >>= 1) s += __shfl_xor(s, off, 64);
  float m = s * (1.0f / 192.0f);
  float d0 = v0 - m, d1 = v1 - m, d2 = v2 - m;
  float ss = d0 * d0 + d1 * d1 + d2 * d2;
#pragma unroll
  for (int off = 32; off > 0; off >>= 1) ss += __shfl_xor(ss, off, 64);
  float inv = rsqrtf(ss * (1.0f / 192.0f) + 1e-5f);
  p[lane] = d0 * inv * g[lane] + bb[lane];
  p[lane + 64] = d1 * inv * g[lane + 64] + bb[lane + 64];
  p[lane + 128] = d2 * inv * g[lane + 128] + bb[lane + 128];
}

// scatter anchor_tok into zeroed anchor_map
__global__ void scatter_kernel(const float* __restrict__ attout,
                               const int* __restrict__ idx,
                               float* __restrict__ amap) {
  int bt = blockIdx.x;
  int b = bt >> 4, t = bt & 15;
  for (int e = threadIdx.x; e < KK * Aa; e += 256) {
    int k = e / Aa, a = e % Aa;
    int n = idx[bt * KK + k];
    amap[((size_t)bt * Nn + n) * Aa + a] =
        attout[((size_t)(b * KK + k) * Tt + t) * Aa + a];
  }
}

// gate MLP + 3-way softmax; one block per b, 192 threads
__global__ void gate_kernel(const float* __restrict__ dppart,
                            const float* __restrict__ appart,
                            const float* __restrict__ w1,
                            const float* __restrict__ b1,
                            const float* __restrict__ w2,
                            const float* __restrict__ b2,
                            float* __restrict__ gw) {
  int b = blockIdx.x;
  __shared__ float sg[2 * Aa];
  __shared__ float sh[Aa];
  int tid = threadIdx.x;
  {
    float d = 0.f;
    for (int t2 = 0; t2 < Tt; ++t2) d += dppart[(b * Tt + t2) * Aa + tid];
    sg[tid] = d * (1.0f / 3136.0f);
    float a = 0.f;
    for (int k2 = 0; k2 < KK; ++k2) a += appart[(b * KK + k2) * Aa + tid];
    sg[Aa + tid] = a * (1.0f / 128.0f);
  }
  __syncthreads();
  {
    const float* w = w1 + (size_t)tid * 2 * Aa;
    float s = b1[tid];
#pragma unroll 8
    for (int j = 0; j < 2 * Aa; ++j) s = fmaf(sg[j], w[j], s);
    sh[tid] = gelu_f(s);
  }
  __syncthreads();
  float v[3];
#pragma unroll
  for (int i = 0; i < 3; ++i) {
    const float* w = w2 + (size_t)(i * Aa + tid) * Aa;
    float s = b2[i * Aa + tid];
#pragma unroll 8
    for (int j = 0; j < Aa; ++j) s = fmaf(sh[j], w[j], s);
    v[i] = s;
  }
  float mx = fmaxf(v[0], fmaxf(v[1], v[2]));
  float e0 = expf(v[0] - mx), e1 = expf(v[1] - mx), e2 = expf(v[2] - mx);
  float inv = 1.0f / (e0 + e1 + e2);
  gw[(b * 3 + 0) * Aa + tid] = e0 * inv;
  gw[(b * 3 + 1) * Aa + tid] = e1 * inv;
  gw[(b * 3 + 2) * Aa + tid] = e2 * inv;
}

// fused = gw0*local + gw1*trans + gw2*amap; fmean[bt,a] = sum_n fused
__global__ void fused_kernel(const float* __restrict__ local,
                             const float* __restrict__ trans,
                             const float* __restrict__ amap,
                             const float* __restrict__ gw,
                             float* __restrict__ fused,
                             float* __restrict__ fmean) {
  int bt = blockIdx.x;
  int b = bt >> 4;
  int a = threadIdx.x;
  float g0 = gw[(b * 3 + 0) * Aa + a];
  float g1 = gw[(b * 3 + 1) * Aa + a];
  float g2 = gw[(b * 3 + 2) * Aa + a];
  size_t base = (size_t)bt * Nn * Aa + a;
  float acc = 0.f;
  for (int n = 0; n < Nn; ++n) {
    size_t o = base + (size_t)n * Aa;
    float f = g0 * local[o] + g1 * trans[o] + g2 * amap[o];
    fused[o] = f;
    acc += f;
  }
  fmean[bt * Aa + a] = acc;
}

// cls_out = cls_tok + (mean_n fused) @ cls_w.T + cls_b
__global__ void cls_kernel(const float* __restrict__ fmean,
                           const float* __restrict__ cw,
                           const float* __restrict__ cb,
                           const float* __restrict__ x,
                           float* __restrict__ out) {
  int bt = blockIdx.x;
  __shared__ float fm[Aa];
  int tid = threadIdx.x;
  if (tid < Aa) fm[tid] = fmean[bt * Aa + tid] * (1.0f / 196.0f);
  __syncthreads();
  for (int c = tid; c < Cc; c += 256) {
    const float* w = cw + (size_t)c * Aa;
    float s = cb[c];
#pragma unroll 8
    for (int a = 0; a < Aa; ++a) s = fmaf(fm[a], w[a], s);
    size_t off = (size_t)bt * (Nn + 1) * Cc + c;
    out[off] = x[off] + s;
  }
}

// ============================================================
extern "C" void kernel_launch(void* const* d_in, const int* in_sizes, int n_in,
                              void* d_out, int out_size, void* d_ws,
                              size_t ws_size, hipStream_t stream) {
  const float* x = (const float*)d_in[0];
  const float* down_w = (const float*)d_in[1];
  const float* down_b = (const float*)d_in[2];
  const float* ldw_w = (const float*)d_in[3];
  const float* lpw_w = (const float*)d_in[4];
  const float* lnorm_g = (const float*)d_in[5];
  const float* lnorm_b = (const float*)d_in[6];
  const float* tdw_w = (const float*)d_in[7];
  const float* tpw_w = (const float*)d_in[8];
  const float* tmlp_w1 = (const float*)d_in[9];
  const float* tmlp_b1 = (const float*)d_in[10];
  const float* tmlp_w2 = (const float*)d_in[11];
  const float* tmlp_b2 = (const float*)d_in[12];
  const float* tnorm_g = (const float*)d_in[13];
  const float* tnorm_b = (const float*)d_in[14];
  const float* attn_in_w = (const float*)d_in[15];
  const float* attn_in_b = (const float*)d_in[16];
  const float* attn_out_w = (const float*)d_in[17];
  const float* attn_out_b = (const float*)d_in[18];
  const float* aproj_w = (const float*)d_in[19];
  const float* aproj_b = (const float*)d_in[20];
  const float* anorm_g = (const float*)d_in[21];
  const float* anorm_b = (const float*)d_in[22];
  const float* gate_w1 = (const float*)d_in[23];
  const float* gate_b1 = (const float*)d_in[24];
  const float* gate_w2 = (const float*)d_in[25];
  const float* gate_b2 = (const float*)d_in[26];
  const float* up_w = (const float*)d_in[27];
  const float* up_b = (const float*)d_in[28];
  const float* cls_w = (const float*)d_in[29];
  const float* cls_b = (const float*)d_in[30];
  float* out = (float*)d_out;

  float* ws = (float*)d_ws;
  float* W0 = ws;              // ph -> trp -> anchor_map
  float* W1 = W0 + SZ;         // delta -> transition
  float* W2 = W1 + SZ;         // attn scratch -> locg/trg -> h1 -> fused
  float* W3 = W2 + 2 * SZ;     // local
  float* sal = W3 + SZ;
  float* attout = sal + BTN;
  float* dppart = attout + (size_t)BKT * Aa;
  float* appart = dppart + (size_t)BT * Aa;
  float* gw = appart + (size_t)Bb * KK * Aa;
  float* fmean = gw + (size_t)Bb * 3 * Aa;
  double* sal64 = (double*)(fmean + (size_t)BT * Aa);  // BT*NCAND doubles
  int* cand = (int*)(sal64 + (size_t)BT * NCAND);      // BT*NCAND ints
  int* idx = cand + (size_t)BT * NCAND;                // BT*KK ints

  // attn-phase scratch lives inside W2 (dead until conv2d)
  float* tok   = W2;                       // 2048*192
  float* qkvb  = tok + (size_t)BKT * Aa;   // 2048*576
  float* obuf  = qkvb + (size_t)BKT * 3 * Aa;  // 2048*192
  float* proj1 = obuf + (size_t)BKT * Aa;  // 2048*192

  // 1. ph = patch @ down_w.T + down_b   (bf16 MFMA)
  gemm_mfma<1, 1, 0><<<dim3(392, 3), 256, 0, stream>>>(
      x, down_w, down_b, W0, nullptr, BTN, Aa, Cc);
  // 2. delta + dp partials
  delta_kernel<<<BT, Aa, 0, stream>>>(W0, W1, dppart);
  // 3. saliency: fp32 candidates -> f64 refine -> exact top-8
  sal_kernel<<<BTN / 4, 256, 0, stream>>>(W1, sal);
  topcand_kernel<<<BT, 64, 0, stream>>>(sal, cand);
  refine_kernel<<<dim3(BT, 2), 192, 0, stream>>>(x, down_w, cand, sal64);
  select_kernel<<<BT, 64, 0, stream>>>(sal64, cand, idx);
  // 4. anchor attention
  gather_kernel<<<BKT, Aa, 0, stream>>>(W0, W1, idx, tok);
  gemm_mfma<0, 1, 0><<<dim3(16, 9), 256, 0, stream>>>(
      tok, attn_in_w, attn_in_b, qkvb, nullptr, BKT, 3 * Aa, Aa);
  attn_core<<<Bb * KK, 256, 0, stream>>>(qkvb, obuf);
  gemm_mfma<0, 1, 0><<<dim3(16, 3), 256, 0, stream>>>(
      obuf, attn_out_w, attn_out_b, proj1, nullptr, BKT, Aa, Aa);
  gemm_mfma<0, 1, 0><<<dim3(16, 3), 256, 0, stream>>>(
      proj1, aproj_w, aproj_b, attout, nullptr, BKT, Aa, Aa);
  appart_kernel<<<Bb * KK, Aa, 0, stream>>>(attout, appart);
  // 5. local branch
  conv2d_kernel<<<(unsigned)(SZ / 256), 256, 0, stream>>>(W0, ldw_w, W2);
  gemm_mfma<0, 0, 0><<<dim3(392, 3), 256, 0, stream>>>(
      W2, lpw_w, nullptr, W3, nullptr, BTN, Aa, Aa);
  ln_kernel<<<BTN / 4, 256, 0, stream>>>(W3, lnorm_g, lnorm_b);
  // 6. transition branch
  conv1d_kernel<<<(unsigned)(SZ / 256), 256, 0, stream>>>(W1, tdw_w, W2);
  gemm_mfma<0, 0, 0><<<dim3(392, 3), 256, 0, stream>>>(
      W2, tpw_w, nullptr, W0, nullptr, BTN, Aa, Aa);
  gemm_mfma<0, 1, 1><<<dim3(392, 6), 256, 0, stream>>>(
      W0, tmlp_w1, tmlp_b1, W2, nullptr, BTN, 2 * Aa, Aa);
  gemm_mfma<0, 1, 0><<<dim3(392, 3), 256, 0, stream>>>(
      W2, tmlp_w2, tmlp_b2, W1, nullptr, BTN, Aa, 2 * Aa);
  ln_kernel<<<BTN / 4, 256, 0, stream>>>(W1, tnorm_g, tnorm_b);
  // 7. anchor map
  hipMemsetAsync(W0, 0, SZ * sizeof(float), stream);
  scatter_kernel<<<BT, 256, 0, stream>>>(attout, idx, W0);
  ln_kernel<<<BTN / 4, 256, 0, stream>>>(W0, anorm_g, anorm_b);
  // 8. gate
  gate_kernel<<<Bb, Aa, 0, stream>>>(dppart, appart, gate_w1, gate_b1,
                                     gate_w2, gate_b2, gw);
  // 9. fuse + output projections
  fused_kernel<<<BT, Aa, 0, stream>>>(W3, W1, W0, gw, W2, fmean);
  gemm_mfma<0, 1, 2><<<dim3(392, 12), 256, 0, stream>>>(
      W2, up_w, up_b, out, x, BTN, Cc, Aa);
  cls_kernel<<<BT, 256, 0, stream>>>(fmean, cls_w, cls_b, x, out);
}

// Round 5
// 648.139 us; speedup vs baseline: 2.2622x; 1.1184x over previous
//
#include <hip/hip_runtime.h>
#include <math.h>

// ---- fixed problem dims ----
constexpr int Bb  = 16;
constexpr int Tt  = 16;
constexpr int Nn  = 196;   // patches (14x14)
constexpr int Cc  = 768;
constexpr int Aa  = 192;
constexpr int KK  = 8;     // TOPK
constexpr int NCAND = 16;  // fp32 candidates refined in f64
constexpr int BT  = Bb * Tt;            // 256
constexpr int BTN = BT * Nn;            // 50176
constexpr int BKT = Bb * KK * Tt;       // 2048 anchor-token rows
constexpr size_t SZ = (size_t)BTN * Aa; // 9,633,792 floats

typedef unsigned short ushortt;
typedef __attribute__((ext_vector_type(8))) short bf16x8;
typedef __attribute__((ext_vector_type(4))) float f32x4;
typedef __attribute__((ext_vector_type(4))) unsigned short u16x4;
typedef __attribute__((ext_vector_type(8))) unsigned short u16x8;

static __device__ __forceinline__ float gelu_f(float x) {
  return 0.5f * x * (1.0f + erff(x * 0.7071067811865476f));
}
static __device__ __forceinline__ ushortt f2bf(float f) {
  unsigned u = __float_as_uint(f);
  u += 0x7FFFu + ((u >> 16) & 1u);  // round-to-nearest-even
  return (ushortt)(u >> 16);
}
static __device__ __forceinline__ float bf2f(ushortt u) {
  return __uint_as_float(((unsigned)u) << 16);
}

// ============================================================
// bf16 MFMA GEMM: C[m,n] = sum_k A[m,k]*W[n,k] (+bias)(+epilogue)
// AT: float (converted to bf16 in staging) or ushort (bf16 in memory).
// CT: float or ushort(bf16) output.
// W fp32 NxK (converted per tile). fp32 accumulate, 16x16x32 MFMA.
// BM=128 BN=64 BK=32, 256 thr = 4 waves (2x2), wave tile 64x32.
// EPI: 0 plain, 1 gelu, 2 mapped residual fp32 (up-proj)
// Grid: (Nc/64, M/128); col-block fastest + XCD-chunked swizzle
// (requires total blocks % 8 == 0 -- true for all launches here).
// ============================================================
template <typename AT, typename CT, int ROWMAP, int BIAS, int EPI>
__global__ __launch_bounds__(256) void gemm_mfma(
    const AT* __restrict__ Ain, const float* __restrict__ W,
    const float* __restrict__ bias, CT* __restrict__ Cout,
    const float* __restrict__ resid, int M, int Nc, int K) {
  constexpr int PIT = 40;  // bf16 pitch (32 + 8 pad) -> worst 2-way (free)
  __shared__ ushortt As[2][128 * PIT];
  __shared__ ushortt Bs[2][64 * PIT];
  const int tid = threadIdx.x;

  // bijective XCD-chunked swizzle, col-block fastest for A-panel reuse
  const int ncb = gridDim.x;
  const int nwg = ncb * gridDim.y;
  const int bid = blockIdx.y * ncb + blockIdx.x;
  const int cpx = nwg >> 3;
  const int swz = (bid & 7) * cpx + (bid >> 3);
  const int row0 = (swz / ncb) * 128;
  const int col0 = (swz % ncb) * 64;

  const int wid = tid >> 6;
  const int lane = tid & 63;
  const int wr = wid >> 1;       // 0..1 -> +64 rows
  const int wc = wid & 1;        // 0..1 -> +32 cols
  const int l15 = lane & 15;
  const int kgrp = lane >> 4;    // 0..3

  const int nsteps = K >> 5;

  // ---- A row pointers ----
  const float* arowf[4];
  const ushortt* arowb[2];
  if constexpr (sizeof(AT) == 4) {
    const int quad = tid & 7, srow = tid >> 3;
#pragma unroll
    for (int p = 0; p < 4; ++p) {
      int r = row0 + srow + 32 * p;
      if (ROWMAP) {
        int bt = r / Nn;
        int n = r - bt * Nn;
        arowf[p] = (const float*)Ain + (size_t)(bt * (Nn + 1) + 1 + n) * K;
      } else {
        arowf[p] = (const float*)Ain + (size_t)r * K;
      }
    }
    (void)quad;
  } else {
    const int srow2 = tid >> 2;
#pragma unroll
    for (int p = 0; p < 2; ++p)
      arowb[p] = (const ushortt*)Ain + (size_t)(row0 + srow2 + 64 * p) * K;
  }
  const float* browp[2];
  {
    const int srow = tid >> 3;
#pragma unroll
    for (int p = 0; p < 2; ++p)
      browp[p] = W + (size_t)(col0 + srow + 32 * p) * K;
  }

  f32x4 acc[4][2];
#pragma unroll
  for (int i = 0; i < 4; ++i)
#pragma unroll
    for (int j = 0; j < 2; ++j) acc[i][j] = (f32x4){0.f, 0.f, 0.f, 0.f};

  float4 apre[4], bpre[2];
  u16x8 apreb[2];

#define STAGE_LOAD(k0)                                                       \
  if constexpr (sizeof(AT) == 4) {                                           \
    const int quad = tid & 7;                                                \
    _Pragma("unroll") for (int p = 0; p < 4; ++p)                            \
        apre[p] = *(const float4*)(arowf[p] + (k0) + quad * 4);              \
  } else {                                                                   \
    const int quad2 = tid & 3;                                               \
    _Pragma("unroll") for (int p = 0; p < 2; ++p)                            \
        apreb[p] = *(const u16x8*)(arowb[p] + (k0) + quad2 * 8);             \
  }                                                                          \
  {                                                                          \
    const int quad = tid & 7;                                                \
    _Pragma("unroll") for (int p = 0; p < 2; ++p)                            \
        bpre[p] = *(const float4*)(browp[p] + (k0) + quad * 4);              \
  }

#define STAGE_WRITE(buf)                                                     \
  if constexpr (sizeof(AT) == 4) {                                           \
    const int quad = tid & 7, srow = tid >> 3;                               \
    _Pragma("unroll") for (int p = 0; p < 4; ++p) {                          \
      u16x4 b = {f2bf(apre[p].x), f2bf(apre[p].y), f2bf(apre[p].z),          \
                 f2bf(apre[p].w)};                                           \
      *(u16x4*)&As[buf][(srow + 32 * p) * PIT + quad * 4] = b;               \
    }                                                                        \
  } else {                                                                   \
    const int quad2 = tid & 3, srow2 = tid >> 2;                             \
    _Pragma("unroll") for (int p = 0; p < 2; ++p)                            \
        *(u16x8*)&As[buf][(srow2 + 64 * p) * PIT + quad2 * 8] = apreb[p];    \
  }                                                                          \
  {                                                                          \
    const int quad = tid & 7, srow = tid >> 3;                               \
    _Pragma("unroll") for (int p = 0; p < 2; ++p) {                          \
      u16x4 b = {f2bf(bpre[p].x), f2bf(bpre[p].y), f2bf(bpre[p].z),          \
                 f2bf(bpre[p].w)};                                           \
      *(u16x4*)&Bs[buf][(srow + 32 * p) * PIT + quad * 4] = b;               \
    }                                                                        \
  }

  STAGE_LOAD(0);
  STAGE_WRITE(0);
  __syncthreads();

  int cur = 0;
  for (int step = 0; step < nsteps; ++step) {
    const bool pref = (step + 1 < nsteps);
    if (pref) {
      int k0 = (step + 1) << 5;
      STAGE_LOAD(k0);
    }
    bf16x8 af[4], bfv[2];
#pragma unroll
    for (int fm = 0; fm < 4; ++fm)
      af[fm] = *(const bf16x8*)&As[cur][(wr * 64 + fm * 16 + l15) * PIT + kgrp * 8];
#pragma unroll
    for (int fn = 0; fn < 2; ++fn)
      bfv[fn] = *(const bf16x8*)&Bs[cur][(wc * 32 + fn * 16 + l15) * PIT + kgrp * 8];
#pragma unroll
    for (int fm = 0; fm < 4; ++fm)
#pragma unroll
      for (int fn = 0; fn < 2; ++fn)
        acc[fm][fn] = __builtin_amdgcn_mfma_f32_16x16x32_bf16(
            af[fm], bfv[fn], acc[fm][fn], 0, 0, 0);
    if (pref) {
      STAGE_WRITE(cur ^ 1);
    }
    __syncthreads();
    cur ^= 1;
  }
#undef STAGE_LOAD
#undef STAGE_WRITE

  // epilogue: C/D layout col=lane&15, row=(lane>>4)*4+j
#pragma unroll
  for (int fm = 0; fm < 4; ++fm) {
    int rbase = row0 + wr * 64 + fm * 16 + kgrp * 4;
#pragma unroll
    for (int fn = 0; fn < 2; ++fn) {
      int c = col0 + wc * 32 + fn * 16 + l15;
      float bv = BIAS ? bias[c] : 0.f;
#pragma unroll
      for (int j = 0; j < 4; ++j) {
        int r = rbase + j;
        float v = acc[fm][fn][j] + bv;
        if (EPI == 1) v = gelu_f(v);
        if (EPI == 2) {
          int bt = r / Nn;
          int n = r - bt * Nn;
          size_t off = (size_t)(bt * (Nn + 1) + 1 + n) * Nc + c;
          ((float*)Cout)[off] = resid[off] + v;
        } else {
          if constexpr (sizeof(CT) == 4)
            Cout[(size_t)r * Nc + c] = (CT)v;
          else
            ((ushortt*)Cout)[(size_t)r * Nc + c] = f2bf(v);
        }
      }
    }
  }
}

// ============================================================
// delta + per-(b,t) |delta| partials
// ============================================================
__global__ void delta_kernel(const float* __restrict__ ph,
                             float* __restrict__ delta,
                             float* __restrict__ dppart) {
  int bt = blockIdx.x;
  int t = bt & 15;
  int a = threadIdx.x;
  const float* cur = ph + (size_t)bt * Nn * Aa + a;
  float* dl = delta + (size_t)bt * Nn * Aa + a;
  float acc = 0.f;
  if (t == 0) {
    for (int n = 0; n < Nn; ++n) dl[(size_t)n * Aa] = 0.f;
  } else {
    const float* prev = cur - (size_t)Nn * Aa;
    for (int n = 0; n < Nn; ++n) {
      float d = cur[(size_t)n * Aa] - prev[(size_t)n * Aa];
      dl[(size_t)n * Aa] = d;
      acc += fabsf(d);
    }
  }
  dppart[bt * Aa + a] = acc;
}

// sal[row] = mean_a |delta[row,a]| (fp32, candidate stage only)
__global__ void sal_kernel(const float* __restrict__ delta,
                           float* __restrict__ sal) {
  int row = blockIdx.x * 4 + (threadIdx.x >> 6);
  int lane = threadIdx.x & 63;
  const float* d = delta + (size_t)row * Aa;
  float s = fabsf(d[lane]) + fabsf(d[lane + 64]) + fabsf(d[lane + 128]);
#pragma unroll
  for (int off = 32; off > 0; off >>= 1) s += __shfl_xor(s, off, 64);
  if (lane == 0) sal[row] = s * (1.0f / 192.0f);
}

// ============================================================
// top-16 fp32 candidates per (b,t); descending val, ties -> smaller n
// ============================================================
__global__ void topcand_kernel(const float* __restrict__ sal,
                               int* __restrict__ cand) {
  int bt = blockIdx.x;
  int lane = threadIdx.x;
  unsigned long long key[4];
#pragma unroll
  for (int j = 0; j < 4; ++j) {
    int n = lane + 64 * j;
    if (n < Nn) {
      unsigned fb = __float_as_uint(sal[(size_t)bt * Nn + n]);
      key[j] = ((unsigned long long)fb << 32) |
               (unsigned long long)(0xFFFFFFFFu - (unsigned)n);
    } else {
      key[j] = 0ULL;
    }
  }
  for (int r = 0; r < NCAND; ++r) {
    unsigned long long m = key[0];
    if (key[1] > m) m = key[1];
    if (key[2] > m) m = key[2];
    if (key[3] > m) m = key[3];
#pragma unroll
    for (int off = 32; off > 0; off >>= 1) {
      unsigned long long o = __shfl_xor(m, off, 64);
      if (o > m) m = o;
    }
    if (lane == 0)
      cand[bt * NCAND + r] = (int)(0xFFFFFFFFu - (unsigned)(m & 0xFFFFFFFFull));
#pragma unroll
    for (int j = 0; j < 4; ++j)
      if (key[j] == m) key[j] = 0ULL;
  }
}

// ============================================================
// f64 refine: sal64 = mean_a |sum_c (x_t - x_{t-1})[n,c] * down_w[a,c]|
// ============================================================
__global__ __launch_bounds__(192) void refine_kernel(
    const float* __restrict__ x, const float* __restrict__ down_w,
    const int* __restrict__ cand, double* __restrict__ sal64) {
  int bt = blockIdx.x;
  int grp = blockIdx.y;
  int t = bt & 15;
  int a = threadIdx.x;
  if (t == 0) {
    if (a < 8) sal64[bt * NCAND + grp * 8 + a] = 0.0;
    return;
  }
  __shared__ double sdiff[8][Cc];
  __shared__ double sabs[8][Aa];
  const float* xt = x + (size_t)bt * (Nn + 1) * Cc;
  const float* xp = xt - (size_t)(Nn + 1) * Cc;
  for (int g = 0; g < 8; ++g) {
    int n = cand[bt * NCAND + grp * 8 + g];
    const float* rt = xt + (size_t)(1 + n) * Cc;
    const float* rp = xp + (size_t)(1 + n) * Cc;
    for (int c = a; c < Cc; c += 192)
      sdiff[g][c] = (double)rt[c] - (double)rp[c];
  }
  __syncthreads();
  double acc[8] = {};
  const float* wrow = down_w + (size_t)a * Cc;
  for (int c0 = 0; c0 < Cc; c0 += 4) {
    float4 w4 = *(const float4*)(wrow + c0);
#pragma unroll
    for (int g = 0; g < 8; ++g) {
      acc[g] += (double)w4.x * sdiff[g][c0] + (double)w4.y * sdiff[g][c0 + 1] +
                (double)w4.z * sdiff[g][c0 + 2] +
                (double)w4.w * sdiff[g][c0 + 3];
    }
  }
#pragma unroll
  for (int g = 0; g < 8; ++g) sabs[g][a] = fabs(acc[g]);
  __syncthreads();
  if (a < 8) {
    double s = 0.0;
    for (int i = 0; i < Aa; ++i) s += sabs[a][i];
    sal64[bt * NCAND + grp * 8 + a] = s * (1.0 / 192.0);
  }
}

// final top-8 by (sal64 desc, n asc)
__global__ void select_kernel(const double* __restrict__ sal64,
                              const int* __restrict__ cand,
                              int* __restrict__ idx) {
  int bt = blockIdx.x;
  int t = bt & 15;
  if (threadIdx.x != 0) return;
  if (t == 0) {
    for (int r = 0; r < KK; ++r) idx[bt * KK + r] = r;
    return;
  }
  double v[NCAND];
  int nn[NCAND];
  bool used[NCAND];
  for (int i = 0; i < NCAND; ++i) {
    v[i] = sal64[bt * NCAND + i];
    nn[i] = cand[bt * NCAND + i];
    used[i] = false;
  }
  for (int r = 0; r < KK; ++r) {
    int best = -1;
    for (int i = 0; i < NCAND; ++i) {
      if (used[i]) continue;
      if (best < 0 || v[i] > v[best] ||
          (v[i] == v[best] && nn[i] < nn[best]))
        best = i;
    }
    used[best] = true;
    idx[bt * KK + r] = nn[best];
  }
}

// ============================================================
// anchor attention: gather -> GEMM qkv -> core -> GEMMs (all fp32, tiny)
// ============================================================
__global__ void gather_kernel(const float* __restrict__ ph,
                              const float* __restrict__ delta,
                              const int* __restrict__ idx,
                              float* __restrict__ tok) {
  int row = blockIdx.x;  // (b*KK+k)*16+t
  int t = row & 15;
  int bk = row >> 4;
  int b = bk >> 3, k = bk & 7;
  int a = threadIdx.x;
  int n = idx[(b * 16 + t) * KK + k];
  size_t off = ((size_t)(b * 16 + t) * Nn + n) * Aa + a;
  tok[(size_t)row * Aa + a] = ph[off] + delta[off];
}

__global__ __launch_bounds__(256) void attn_core(
    const float* __restrict__ qkv, float* __restrict__ o) {
  constexpr int P = 580;
  __shared__ float sq[16 * P];
  __shared__ float ssc[4][16][17];
  int bk = blockIdx.x;
  int tid = threadIdx.x;
  const float* src = qkv + (size_t)bk * 16 * 576;
  for (int e = tid; e < 16 * 144; e += 256) {
    int r = e / 144, c4 = e % 144;
    float4 v = *(const float4*)(src + r * 576 + c4 * 4);
    *(float4*)(&sq[r * P + c4 * 4]) = v;
  }
  __syncthreads();
  int h = tid >> 6, lane = tid & 63;
#pragma unroll
  for (int s4 = 0; s4 < 4; ++s4) {
    int e = lane + 64 * s4;
    int i = e >> 4, j = e & 15;
    const float* q = sq + i * P + h * 48;
    const float* k2 = sq + j * P + 192 + h * 48;
    float s = 0.f;
#pragma unroll
    for (int d = 0; d < 48; ++d) s = fmaf(q[d], k2[d], s);
    ssc[h][i][j] = s * 0.14433756729740643f;  // 1/sqrt(48)
  }
  __syncthreads();
  if (lane < 16) {
    float* r = ssc[h][lane];
    float mx = r[0];
    for (int j = 1; j < 16; ++j) mx = fmaxf(mx, r[j]);
    float sum = 0.f;
    for (int j = 0; j < 16; ++j) {
      float ev = expf(r[j] - mx);
      r[j] = ev;
      sum += ev;
    }
    float inv = 1.0f / sum;
    for (int j = 0; j < 16; ++j) r[j] *= inv;
  }
  __syncthreads();
#pragma unroll
  for (int s4 = 0; s4 < 12; ++s4) {
    int e = lane + 64 * s4;
    int i = e / 48, d = e - i * 48;
    float s = 0.f;
#pragma unroll
    for (int j = 0; j < 16; ++j)
      s = fmaf(ssc[h][i][j], sq[j * P + 384 + h * 48 + d], s);
    o[((size_t)bk * 16 + i) * 192 + h * 48 + d] = s;
  }
}

__global__ void appart_kernel(const float* __restrict__ attout,
                              float* __restrict__ appart) {
  int bk = blockIdx.x;
  int a = threadIdx.x;
  float s = 0.f;
  for (int t = 0; t < Tt; ++t)
    s += attout[((size_t)bk * Tt + t) * Aa + a];
  appart[bk * Aa + a] = s;
}

// depthwise 3x3 SAME conv over 14x14 + gelu -> bf16
__global__ void conv2d_kernel(const float* __restrict__ ph,
                              const float* __restrict__ ldw,
                              ushortt* __restrict__ og) {
  size_t e = (size_t)blockIdx.x * 256 + threadIdx.x;
  int a = (int)(e % Aa);
  size_t r = e / Aa;
  int n = (int)(r % Nn);
  int bt = (int)(r / Nn);
  int y = n / 14, x = n % 14;
  const float* base = ph + (size_t)bt * Nn * Aa + a;
  const float* w = ldw + a * 9;
  float s = 0.f;
#pragma unroll
  for (int dy = -1; dy <= 1; ++dy) {
    int yy = y + dy;
    if (yy < 0 || yy >= 14) continue;
#pragma unroll
    for (int dx = -1; dx <= 1; ++dx) {
      int xc = x + dx;
      if (xc < 0 || xc >= 14) continue;
      s = fmaf(base[(size_t)(yy * 14 + xc) * Aa], w[(dy + 1) * 3 + (dx + 1)], s);
    }
  }
  og[e] = f2bf(gelu_f(s));
}

// depthwise k=3 SAME conv over t + gelu -> bf16
__global__ void conv1d_kernel(const float* __restrict__ delta,
                              const float* __restrict__ tdw,
                              ushortt* __restrict__ og) {
  size_t e = (size_t)blockIdx.x * 256 + threadIdx.x;
  int a = (int)(e % Aa);
  size_t r = e / Aa;
  int n = (int)(r % Nn);
  int bt = (int)(r / Nn);
  int t = bt & 15, b = bt >> 4;
  const float* w = tdw + a * 3;
  float s = 0.f;
#pragma unroll
  for (int j = 0; j < 3; ++j) {
    int tt = t + j - 1;
    if (tt >= 0 && tt < Tt)
      s = fmaf(delta[((size_t)(b * Tt + tt) * Nn + n) * Aa + a], w[j], s);
  }
  og[e] = f2bf(gelu_f(s));
}

// in-place LayerNorm over last dim (192); one wave per row; T = float/bf16
template <typename T>
__global__ void ln_kernel(T* __restrict__ buf, const float* __restrict__ g,
                          const float* __restrict__ bb) {
  size_t row = (size_t)blockIdx.x * 4 + (threadIdx.x >> 6);
  int lane = threadIdx.x & 63;
  T* p = buf + row * Aa;
  float v0, v1, v2;
  if constexpr (sizeof(T) == 4) {
    v0 = p[lane]; v1 = p[lane + 64]; v2 = p[lane + 128];
  } else {
    v0 = bf2f(p[lane]); v1 = bf2f(p[lane + 64]); v2 = bf2f(p[lane + 128]);
  }
  float s = v0 + v1 + v2;
#pragma unroll
  for (int off = 32; off > 0; off >>= 1) s += __shfl_xor(s, off, 64);
  float m = s * (1.0f / 192.0f);
  float d0 = v0 - m, d1 = v1 - m, d2 = v2 - m;
  float ss = d0 * d0 + d1 * d1 + d2 * d2;
#pragma unroll
  for (int off = 32; off > 0; off >>= 1) ss += __shfl_xor(ss, off, 64);
  float inv = rsqrtf(ss * (1.0f / 192.0f) + 1e-5f);
  float o0 = d0 * inv * g[lane] + bb[lane];
  float o1 = d1 * inv * g[lane + 64] + bb[lane + 64];
  float o2 = d2 * inv * g[lane + 128] + bb[lane + 128];
  if constexpr (sizeof(T) == 4) {
    p[lane] = o0; p[lane + 64] = o1; p[lane + 128] = o2;
  } else {
    p[lane] = f2bf(o0); p[lane + 64] = f2bf(o1); p[lane + 128] = f2bf(o2);
  }
}

// scatter anchor_tok into zeroed bf16 anchor_map
__global__ void scatter_kernel(const float* __restrict__ attout,
                               const int* __restrict__ idx,
                               ushortt* __restrict__ amap) {
  int bt = blockIdx.x;
  int b = bt >> 4, t = bt & 15;
  for (int e = threadIdx.x; e < KK * Aa; e += 256) {
    int k = e / Aa, a = e % Aa;
    int n = idx[bt * KK + k];
    amap[((size_t)bt * Nn + n) * Aa + a] =
        f2bf(attout[((size_t)(b * KK + k) * Tt + t) * Aa + a]);
  }
}

// gate MLP + 3-way softmax; one block per b, 192 threads
__global__ void gate_kernel(const float* __restrict__ dppart,
                            const float* __restrict__ appart,
                            const float* __restrict__ w1,
                            const float* __restrict__ b1,
                            const float* __restrict__ w2,
                            const float* __restrict__ b2,
                            float* __restrict__ gw) {
  int b = blockIdx.x;
  __shared__ float sg[2 * Aa];
  __shared__ float sh[Aa];
  int tid = threadIdx.x;
  {
    float d = 0.f;
    for (int t2 = 0; t2 < Tt; ++t2) d += dppart[(b * Tt + t2) * Aa + tid];
    sg[tid] = d * (1.0f / 3136.0f);
    float a = 0.f;
    for (int k2 = 0; k2 < KK; ++k2) a += appart[(b * KK + k2) * Aa + tid];
    sg[Aa + tid] = a * (1.0f / 128.0f);
  }
  __syncthreads();
  {
    const float* w = w1 + (size_t)tid * 2 * Aa;
    float s = b1[tid];
#pragma unroll 8
    for (int j = 0; j < 2 * Aa; ++j) s = fmaf(sg[j], w[j], s);
    sh[tid] = gelu_f(s);
  }
  __syncthreads();
  float v[3];
#pragma unroll
  for (int i = 0; i < 3; ++i) {
    const float* w = w2 + (size_t)(i * Aa + tid) * Aa;
    float s = b2[i * Aa + tid];
#pragma unroll 8
    for (int j = 0; j < Aa; ++j) s = fmaf(sh[j], w[j], s);
    v[i] = s;
  }
  float mx = fmaxf(v[0], fmaxf(v[1], v[2]));
  float e0 = expf(v[0] - mx), e1 = expf(v[1] - mx), e2 = expf(v[2] - mx);
  float inv = 1.0f / (e0 + e1 + e2);
  gw[(b * 3 + 0) * Aa + tid] = e0 * inv;
  gw[(b * 3 + 1) * Aa + tid] = e1 * inv;
  gw[(b * 3 + 2) * Aa + tid] = e2 * inv;
}

// fused = gw0*local + gw1*trans + gw2*amap (bf16 in/out); fmean fp32
__global__ void fused_kernel(const ushortt* __restrict__ local,
                             const ushortt* __restrict__ trans,
                             const ushortt* __restrict__ amap,
                             const float* __restrict__ gw,
                             ushortt* __restrict__ fused,
                             float* __restrict__ fmean) {
  int bt = blockIdx.x;
  int b = bt >> 4;
  int a = threadIdx.x;
  float g0 = gw[(b * 3 + 0) * Aa + a];
  float g1 = gw[(b * 3 + 1) * Aa + a];
  float g2 = gw[(b * 3 + 2) * Aa + a];
  size_t base = (size_t)bt * Nn * Aa + a;
  float acc = 0.f;
  for (int n = 0; n < Nn; ++n) {
    size_t o = base + (size_t)n * Aa;
    float f = g0 * bf2f(local[o]) + g1 * bf2f(trans[o]) + g2 * bf2f(amap[o]);
    fused[o] = f2bf(f);
    acc += f;
  }
  fmean[bt * Aa + a] = acc;
}

// cls_out = cls_tok + (mean_n fused) @ cls_w.T + cls_b
__global__ void cls_kernel(const float* __restrict__ fmean,
                           const float* __restrict__ cw,
                           const float* __restrict__ cb,
                           const float* __restrict__ x,
                           float* __restrict__ out) {
  int bt = blockIdx.x;
  __shared__ float fm[Aa];
  int tid = threadIdx.x;
  if (tid < Aa) fm[tid] = fmean[bt * Aa + tid] * (1.0f / 196.0f);
  __syncthreads();
  for (int c = tid; c < Cc; c += 256) {
    const float* w = cw + (size_t)c * Aa;
    float s = cb[c];
#pragma unroll 8
    for (int a = 0; a < Aa; ++a) s = fmaf(fm[a], w[a], s);
    size_t off = (size_t)bt * (Nn + 1) * Cc + c;
    out[off] = x[off] + s;
  }
}

// ============================================================
extern "C" void kernel_launch(void* const* d_in, const int* in_sizes, int n_in,
                              void* d_out, int out_size, void* d_ws,
                              size_t ws_size, hipStream_t stream) {
  const float* x = (const float*)d_in[0];
  const float* down_w = (const float*)d_in[1];
  const float* down_b = (const float*)d_in[2];
  const float* ldw_w = (const float*)d_in[3];
  const float* lpw_w = (const float*)d_in[4];
  const float* lnorm_g = (const float*)d_in[5];
  const float* lnorm_b = (const float*)d_in[6];
  const float* tdw_w = (const float*)d_in[7];
  const float* tpw_w = (const float*)d_in[8];
  const float* tmlp_w1 = (const float*)d_in[9];
  const float* tmlp_b1 = (const float*)d_in[10];
  const float* tmlp_w2 = (const float*)d_in[11];
  const float* tmlp_b2 = (const float*)d_in[12];
  const float* tnorm_g = (const float*)d_in[13];
  const float* tnorm_b = (const float*)d_in[14];
  const float* attn_in_w = (const float*)d_in[15];
  const float* attn_in_b = (const float*)d_in[16];
  const float* attn_out_w = (const float*)d_in[17];
  const float* attn_out_b = (const float*)d_in[18];
  const float* aproj_w = (const float*)d_in[19];
  const float* aproj_b = (const float*)d_in[20];
  const float* anorm_g = (const float*)d_in[21];
  const float* anorm_b = (const float*)d_in[22];
  const float* gate_w1 = (const float*)d_in[23];
  const float* gate_b1 = (const float*)d_in[24];
  const float* gate_w2 = (const float*)d_in[25];
  const float* gate_b2 = (const float*)d_in[26];
  const float* up_w = (const float*)d_in[27];
  const float* up_b = (const float*)d_in[28];
  const float* cls_w = (const float*)d_in[29];
  const float* cls_b = (const float*)d_in[30];
  float* out = (float*)d_out;

  float* ws = (float*)d_ws;
  float* W0 = ws;              // ph fp32 -> trp bf16 -> amap bf16
  float* W1 = W0 + SZ;         // delta fp32 -> transition bf16
  float* W2 = W1 + SZ;         // attn scratch fp32 -> locg/trg/h1/fused bf16
  float* W3 = W2 + 2 * SZ;     // local bf16
  float* sal = W3 + SZ;
  float* attout = sal + BTN;
  float* dppart = attout + (size_t)BKT * Aa;
  float* appart = dppart + (size_t)BT * Aa;
  float* gw = appart + (size_t)Bb * KK * Aa;
  float* fmean = gw + (size_t)Bb * 3 * Aa;
  double* sal64 = (double*)(fmean + (size_t)BT * Aa);  // BT*NCAND doubles
  int* cand = (int*)(sal64 + (size_t)BT * NCAND);      // BT*NCAND ints
  int* idx = cand + (size_t)BT * NCAND;                // BT*KK ints

  // bf16 views
  ushortt* trp_b   = (ushortt*)W0;
  ushortt* amap_b  = (ushortt*)W0;
  ushortt* trans_b = (ushortt*)W1;
  ushortt* locg_b  = (ushortt*)W2;
  ushortt* trg_b   = (ushortt*)W2;
  ushortt* h1_b    = (ushortt*)W2;
  ushortt* fused_b = (ushortt*)W2;
  ushortt* local_b = (ushortt*)W3;

  // attn-phase fp32 scratch lives inside W2 (dead until conv2d)
  float* tok   = W2;                       // 2048*192
  float* qkvb  = tok + (size_t)BKT * Aa;   // 2048*576
  float* obuf  = qkvb + (size_t)BKT * 3 * Aa;  // 2048*192
  float* proj1 = obuf + (size_t)BKT * Aa;  // 2048*192

  // 1. ph = patch @ down_w.T + down_b (fp32 out; feeds delta/ranking)
  gemm_mfma<float, float, 1, 1, 0><<<dim3(3, 392), 256, 0, stream>>>(
      x, down_w, down_b, W0, nullptr, BTN, Aa, Cc);
  // 2. delta + dp partials
  delta_kernel<<<BT, Aa, 0, stream>>>(W0, W1, dppart);
  // 3. saliency: fp32 candidates -> f64 refine -> exact top-8
  sal_kernel<<<BTN / 4, 256, 0, stream>>>(W1, sal);
  topcand_kernel<<<BT, 64, 0, stream>>>(sal, cand);
  refine_kernel<<<dim3(BT, 2), 192, 0, stream>>>(x, down_w, cand, sal64);
  select_kernel<<<BT, 64, 0, stream>>>(sal64, cand, idx);
  // 4. anchor attention (fp32, tiny)
  gather_kernel<<<BKT, Aa, 0, stream>>>(W0, W1, idx, tok);
  gemm_mfma<float, float, 0, 1, 0><<<dim3(9, 16), 256, 0, stream>>>(
      tok, attn_in_w, attn_in_b, qkvb, nullptr, BKT, 3 * Aa, Aa);
  attn_core<<<Bb * KK, 256, 0, stream>>>(qkvb, obuf);
  gemm_mfma<float, float, 0, 1, 0><<<dim3(3, 16), 256, 0, stream>>>(
      obuf, attn_out_w, attn_out_b, proj1, nullptr, BKT, Aa, Aa);
  gemm_mfma<float, float, 0, 1, 0><<<dim3(3, 16), 256, 0, stream>>>(
      proj1, aproj_w, aproj_b, attout, nullptr, BKT, Aa, Aa);
  appart_kernel<<<Bb * KK, Aa, 0, stream>>>(attout, appart);
  // 5. local branch (bf16 streams)
  conv2d_kernel<<<(unsigned)(SZ / 256), 256, 0, stream>>>(W0, ldw_w, locg_b);
  gemm_mfma<ushortt, ushortt, 0, 0, 0><<<dim3(3, 392), 256, 0, stream>>>(
      locg_b, lpw_w, nullptr, local_b, nullptr, BTN, Aa, Aa);
  ln_kernel<ushortt><<<BTN / 4, 256, 0, stream>>>(local_b, lnorm_g, lnorm_b);
  // 6. transition branch (bf16 streams)
  conv1d_kernel<<<(unsigned)(SZ / 256), 256, 0, stream>>>(W1, tdw_w, trg_b);
  gemm_mfma<ushortt, ushortt, 0, 0, 0><<<dim3(3, 392), 256, 0, stream>>>(
      trg_b, tpw_w, nullptr, trp_b, nullptr, BTN, Aa, Aa);
  gemm_mfma<ushortt, ushortt, 0, 1, 1><<<dim3(6, 392), 256, 0, stream>>>(
      trp_b, tmlp_w1, tmlp_b1, h1_b, nullptr, BTN, 2 * Aa, Aa);
  gemm_mfma<ushortt, ushortt, 0, 1, 0><<<dim3(3, 392), 256, 0, stream>>>(
      h1_b, tmlp_w2, tmlp_b2, trans_b, nullptr, BTN, Aa, 2 * Aa);
  ln_kernel<ushortt><<<BTN / 4, 256, 0, stream>>>(trans_b, tnorm_g, tnorm_b);
  // 7. anchor map (bf16)
  hipMemsetAsync(amap_b, 0, SZ * sizeof(ushortt), stream);
  scatter_kernel<<<BT, 256, 0, stream>>>(attout, idx, amap_b);
  ln_kernel<ushortt><<<BTN / 4, 256, 0, stream>>>(amap_b, anorm_g, anorm_b);
  // 8. gate
  gate_kernel<<<Bb, Aa, 0, stream>>>(dppart, appart, gate_w1, gate_b1,
                                     gate_w2, gate_b2, gw);
  // 9. fuse + output projections
  fused_kernel<<<BT, Aa, 0, stream>>>(local_b, trans_b, amap_b, gw, fused_b,
                                      fmean);
  gemm_mfma<ushortt, float, 0, 1, 2><<<dim3(12, 392), 256, 0, stream>>>(
      fused_b, up_w, up_b, out, x, BTN, Cc, Aa);
  cls_kernel<<<BT, 256, 0, stream>>>(fmean, cls_w, cls_b, x, out);
}